// Round 11
// baseline (330.729 us; speedup 1.0000x reference)
//
#include <hip/hip_runtime.h>
#include <float.h>

#define BATCH 4
#define LSEQ  2048
#define DMODEL 512
#define NH    8
#define DHD   64
#define NSAMP 40
#define NTOP  40
#define NCHUNK 32
#define TK    64
#define QK_SCALE 0.125f

typedef unsigned short u16;
typedef __attribute__((ext_vector_type(8))) short short8b;  // 8 bf16 = 16 B
typedef __attribute__((ext_vector_type(4))) float f32x4;
typedef __attribute__((ext_vector_type(4))) float f32x4v;   // for nontemporal ld

#define ASTRIDE ((size_t)BATCH * LSEQ * DMODEL)   // 4,194,304 elems (2^22)
#define WSTRIDE ((size_t)DMODEL * DMODEL)         //   262,144 elems (2^18)

// RTNE float->bf16 on raw bits (inputs finite).
static __device__ __forceinline__ u16 f2bf(float x) {
    unsigned u = __float_as_uint(x);
    u += 0x7FFFu + ((u >> 16) & 1u);
    return (u16)(u >> 16);
}
static __device__ __forceinline__ float bf2f(u16 s) {
    return __uint_as_float((unsigned)s << 16);
}

// ---------------------------------------------------------------------------
// K0: unified 3-way bf16 split, ONE dispatch. x = p1+p2+p3 + O(2^-27|x|).
// ---------------------------------------------------------------------------
__global__ __launch_bounds__(256) void split3_all(
    const float* __restrict__ x, const float* __restrict__ ctxin,
    const float* __restrict__ Wq, const float* __restrict__ Wk,
    const float* __restrict__ Wv,
    u16* __restrict__ xsP, u16* __restrict__ csP,
    u16* __restrict__ wqP, u16* __restrict__ wkP, u16* __restrict__ wvP)
{
    const int X4 = 1 << 20;                 // float4s in x / ctx
    const int W4 = 1 << 16;                 // float4s in each W
    const int total = 2 * X4 + 3 * W4;
    for (int i = blockIdx.x * 256 + threadIdx.x; i < total; i += gridDim.x * 256) {
        const float* src; u16* dst; size_t pstride; int i4;
        if (i < X4)            { src = x;     dst = xsP; pstride = ASTRIDE; i4 = i; }
        else if (i < 2 * X4)   { src = ctxin; dst = csP; pstride = ASTRIDE; i4 = i - X4; }
        else {
            const int w = i - 2 * X4;
            const int which = w >> 16, rem = w & (W4 - 1);
            src = (which == 0) ? Wq : (which == 1) ? Wk : Wv;
            dst = (which == 0) ? wqP : (which == 1) ? wkP : wvP;
            pstride = WSTRIDE; i4 = rem;
        }
        const float4 v = reinterpret_cast<const float4*>(src)[i4];
        const float in[4] = {v.x, v.y, v.z, v.w};
        ushort4 o1, o2, o3;
        u16 b1[4], b2[4], b3[4];
#pragma unroll
        for (int c = 0; c < 4; ++c) {
            const float xx = in[c];
            b1[c] = f2bf(xx);
            const float r1 = xx - bf2f(b1[c]);
            b2[c] = f2bf(r1);
            b3[c] = f2bf(r1 - bf2f(b2[c]));
        }
        o1.x = b1[0]; o1.y = b1[1]; o1.z = b1[2]; o1.w = b1[3];
        o2.x = b2[0]; o2.y = b2[1]; o2.z = b2[2]; o2.w = b2[3];
        o3.x = b3[0]; o3.y = b3[1]; o3.z = b3[2]; o3.w = b3[3];
        reinterpret_cast<ushort4*>(dst)[i4]                = o1;
        reinterpret_cast<ushort4*>(dst + pstride)[i4]      = o2;
        reinterpret_cast<ushort4*>(dst + 2 * pstride)[i4]  = o3;
    }
}

// ---------------------------------------------------------------------------
// K1: GEMM on MFMA, bf16xNP pre-split planes. C = A @ W^T + b.
// NP=3 (Q,K): 6 products 11,12,21,13,31,22 — fp32-GEMM accuracy (top-k safe).
// NP=2 (V):   3 products 11,12,21 — error ~1e-5, 400x below threshold; V
//             never feeds top-k selection. 1/3 less LDS traffic and MFMA.
// Tile 128x128, 4 waves 2x2, wave 64x64. Pad-40 rows: 2-way banks (free).
// XCD-chunked decode. Async reg-staged next tile.
// Two dispatches (QK grid (256,2), V grid (256,1)) — ALSO gives profile
// attribution: any tail kernel > ~56 us must now surface in top-5.
// ---------------------------------------------------------------------------
template<int NP>
__global__ __launch_bounds__(256) void gemm_mfma(
    const u16* __restrict__ A0, const u16* __restrict__ W0,
    const u16* __restrict__ A1, const u16* __restrict__ W1,
    const float* __restrict__ bias0, const float* __restrict__ bias1,
    float* __restrict__ Out0, float* __restrict__ Out1)
{
    const int z = blockIdx.y;
    const int i = blockIdx.x;            // 0..255
    const int xcd = i & 7;
    const int loc = i >> 3;              // 0..31
    const int m0 = (xcd * 8 + (loc & 7)) * 128;
    const int n0 = (loc >> 3) * 128;

    const u16* __restrict__ Ap   = z ? A1 : A0;
    const u16* __restrict__ Wp   = z ? W1 : W0;
    const float* __restrict__ bias = z ? bias1 : bias0;
    float*       __restrict__ Out  = z ? Out1 : Out0;

    __shared__ u16 As[NP][128][40];   // NP=3: 30720 B; NP=2: 20480 B
    __shared__ u16 Ws[NP][128][40];

    const int tid  = threadIdx.x;
    const int w    = tid >> 6;
    const int lane = tid & 63;
    const int wm   = w >> 1;
    const int wn   = w & 1;
    const int lr   = lane & 15;
    const int lg   = lane >> 4;

    const int srow = tid >> 1;       // 0..127
    const int sc   = (tid & 1) * 16; // 16 bf16 = 2 short8b per row-half

    f32x4 acc[4][4];
#pragma unroll
    for (int mf = 0; mf < 4; ++mf)
#pragma unroll
        for (int nf = 0; nf < 4; ++nf)
#pragma unroll
            for (int r = 0; r < 4; ++r) acc[mf][nf][r] = 0.f;

    short8b sa[NP][2], sw[NP][2];
#pragma unroll
    for (int p = 0; p < NP; ++p) {
        const u16* asrc = Ap + p * ASTRIDE + (size_t)(m0 + srow) * DMODEL + sc;
        const u16* wsrc = Wp + p * WSTRIDE + (size_t)(n0 + srow) * DMODEL + sc;
        sa[p][0] = *reinterpret_cast<const short8b*>(asrc);
        sa[p][1] = *reinterpret_cast<const short8b*>(asrc + 8);
        sw[p][0] = *reinterpret_cast<const short8b*>(wsrc);
        sw[p][1] = *reinterpret_cast<const short8b*>(wsrc + 8);
    }

    for (int k0 = 0; k0 < DMODEL; k0 += 32) {
#pragma unroll
        for (int p = 0; p < NP; ++p) {
            *reinterpret_cast<short8b*>(&As[p][srow][sc])     = sa[p][0];
            *reinterpret_cast<short8b*>(&As[p][srow][sc + 8]) = sa[p][1];
            *reinterpret_cast<short8b*>(&Ws[p][srow][sc])     = sw[p][0];
            *reinterpret_cast<short8b*>(&Ws[p][srow][sc + 8]) = sw[p][1];
        }
        __syncthreads();

        if (k0 + 32 < DMODEL) {
#pragma unroll
            for (int p = 0; p < NP; ++p) {
                const u16* asrc =
                    Ap + p * ASTRIDE + (size_t)(m0 + srow) * DMODEL + k0 + 32 + sc;
                const u16* wsrc =
                    Wp + p * WSTRIDE + (size_t)(n0 + srow) * DMODEL + k0 + 32 + sc;
                sa[p][0] = *reinterpret_cast<const short8b*>(asrc);
                sa[p][1] = *reinterpret_cast<const short8b*>(asrc + 8);
                sw[p][0] = *reinterpret_cast<const short8b*>(wsrc);
                sw[p][1] = *reinterpret_cast<const short8b*>(wsrc + 8);
            }
        }

        short8b af[4][NP];
#pragma unroll
        for (int mf = 0; mf < 4; ++mf) {
            const int row = wm * 64 + mf * 16 + lr;
#pragma unroll
            for (int p = 0; p < NP; ++p)
                af[mf][p] = *reinterpret_cast<const short8b*>(&As[p][row][lg * 8]);
        }
#pragma unroll
        for (int nf = 0; nf < 4; ++nf) {
            const int row = wn * 64 + nf * 16 + lr;
            const short8b b1 = *reinterpret_cast<const short8b*>(&Ws[0][row][lg * 8]);
            const short8b b2 = *reinterpret_cast<const short8b*>(&Ws[1][row][lg * 8]);
#pragma unroll
            for (int mf = 0; mf < 4; ++mf) {
                acc[mf][nf] = __builtin_amdgcn_mfma_f32_16x16x32_bf16(af[mf][0], b1, acc[mf][nf], 0, 0, 0);
                acc[mf][nf] = __builtin_amdgcn_mfma_f32_16x16x32_bf16(af[mf][1], b1, acc[mf][nf], 0, 0, 0);
                acc[mf][nf] = __builtin_amdgcn_mfma_f32_16x16x32_bf16(af[mf][0], b2, acc[mf][nf], 0, 0, 0);
                if constexpr (NP == 3) {
                    const short8b b3 = *reinterpret_cast<const short8b*>(&Ws[2][row][lg * 8]);
                    acc[mf][nf] = __builtin_amdgcn_mfma_f32_16x16x32_bf16(af[mf][2], b1, acc[mf][nf], 0, 0, 0);
                    acc[mf][nf] = __builtin_amdgcn_mfma_f32_16x16x32_bf16(af[mf][0], b3, acc[mf][nf], 0, 0, 0);
                    acc[mf][nf] = __builtin_amdgcn_mfma_f32_16x16x32_bf16(af[mf][1], b2, acc[mf][nf], 0, 0, 0);
                }
            }
        }
        __syncthreads();
    }

    // epilogue: C col = lane&15 (n), row = lg*4 + r (m-local)
#pragma unroll
    for (int nf = 0; nf < 4; ++nf) {
        const int n = n0 + wn * 64 + nf * 16 + lr;
        const int h = n >> 6, d = n & 63;
        const float bv_ = bias[n];
#pragma unroll
        for (int mf = 0; mf < 4; ++mf) {
#pragma unroll
            for (int r = 0; r < 4; ++r) {
                const int m = m0 + wm * 64 + mf * 16 + lg * 4 + r;
                const int b = m >> 11, l = m & (LSEQ - 1);
                Out[((size_t)(b * NH + h) * LSEQ + l) * DHD + d] = acc[mf][nf][r] + bv_;
            }
        }
    }
}

// ---------------------------------------------------------------------------
// K2: sampled sparsity measure + zero-init of headmask/VmeanRaw.
// Q loads NONTEMPORAL: the one-shot 16MB Q stream must not evict the 2MB/XCD
// K gather set from L2 (suspected cause of score being L3-latency-bound).
// ---------------------------------------------------------------------------
__global__ __launch_bounds__(256) void score_kernel(
    const float* __restrict__ Qt, const float* __restrict__ Kt,
    const int* __restrict__ idxs, float* __restrict__ M,
    unsigned* __restrict__ headmask, float* __restrict__ VmeanRaw)
{
    const int flat = blockIdx.x;             // 16384 blocks
    if (flat < 32) headmask[flat * 256 + threadIdx.x] = 0u;
    else if (flat < 40) VmeanRaw[(flat - 32) * 256 + threadIdx.x] = 0.f;

    const int xcd  = flat & 7;
    const int slot = flat >> 3;              // 0..2047
    const int bh   = xcd * 4 + (slot >> 9);  // 4 bh per XCD, K L2-resident
    const int w    = threadIdx.x >> 6;
    const int lane = threadIdx.x & 63;
    const int l    = (slot & 511) * 4 + w;

    const int g  = lane >> 4;
    const int dl = lane & 15;

#if defined(__has_builtin) && __has_builtin(__builtin_nontemporal_load)
    const f32x4v q4 = __builtin_nontemporal_load(
        reinterpret_cast<const f32x4v*>(Qt + ((size_t)bh * LSEQ + l) * DHD + dl * 4));
#else
    const f32x4v q4 = *reinterpret_cast<const f32x4v*>(
        Qt + ((size_t)bh * LSEQ + l) * DHD + dl * 4);
#endif

    const float* Kb = Kt + (size_t)bh * LSEQ * DHD;
    float vmax = -FLT_MAX, vsum = 0.f;
#pragma unroll
    for (int it = 0; it < 10; ++it) {
        const int s = it * 4 + g;
        const int ks = idxs[l * NSAMP + s];
        const float4 k4 = *reinterpret_cast<const float4*>(
            Kb + (size_t)ks * DHD + dl * 4);
        float p = q4[0] * k4.x + q4[1] * k4.y + q4[2] * k4.z + q4[3] * k4.w;
        p += __shfl_xor(p, 1);
        p += __shfl_xor(p, 2);
        p += __shfl_xor(p, 4);
        p += __shfl_xor(p, 8);
        vmax = fmaxf(vmax, p);
        vsum += p;
    }
    vmax = fmaxf(vmax, __shfl_xor(vmax, 16));
    vsum += __shfl_xor(vsum, 16);
    vmax = fmaxf(vmax, __shfl_xor(vmax, 32));
    vsum += __shfl_xor(vsum, 32);
    if (lane == 0) M[(size_t)bh * LSEQ + l] = vmax - vsum * (1.0f / LSEQ);
}

// ---------------------------------------------------------------------------
// K3: stable top-40 per (b,h); candidates in registers.
// ---------------------------------------------------------------------------
__global__ __launch_bounds__(256) void topk_kernel(
    const float* __restrict__ M, int* __restrict__ topidx,
    unsigned* __restrict__ headmask, unsigned char* __restrict__ slot)
{
    const int bh = blockIdx.x;
    const int b = bh >> 3, h = bh & 7;
    const int w = threadIdx.x >> 6, lane = threadIdx.x & 63;
    const int base = threadIdx.x * 8;

    float e[8];
    {
        const float4 v0 = *reinterpret_cast<const float4*>(M + (size_t)bh * LSEQ + base);
        const float4 v1 = *reinterpret_cast<const float4*>(M + (size_t)bh * LSEQ + base + 4);
        e[0] = v0.x; e[1] = v0.y; e[2] = v0.z; e[3] = v0.w;
        e[4] = v1.x; e[5] = v1.y; e[6] = v1.z; e[7] = v1.w;
    }

    __shared__ float rv[4];
    __shared__ int   ri[4];
    __shared__ int   winner;

    for (int t = 0; t < NTOP; ++t) {
        float bv = e[0]; int br = 0;
#pragma unroll
        for (int r = 1; r < 8; ++r)
            if (e[r] > bv) { bv = e[r]; br = r; }
        int bi = base + br;
#pragma unroll
        for (int off = 32; off; off >>= 1) {
            const float ov = __shfl_xor(bv, off);
            const int   oi = __shfl_xor(bi, off);
            if (ov > bv || (ov == bv && oi < bi)) { bv = ov; bi = oi; }
        }
        if (lane == 0) { rv[w] = bv; ri[w] = bi; }
        __syncthreads();
        if (threadIdx.x == 0) {
            float fv = rv[0]; int fi = ri[0];
#pragma unroll
            for (int k = 1; k < 4; ++k)
                if (rv[k] > fv || (rv[k] == fv && ri[k] < fi)) { fv = rv[k]; fi = ri[k]; }
            topidx[bh * NTOP + t] = fi;
            atomicOr(&headmask[b * LSEQ + fi], 1u << h);
            slot[bh * LSEQ + fi] = (unsigned char)t;
            winner = fi;
        }
        __syncthreads();
        const int fi = winner;
        if ((fi >> 3) == threadIdx.x) e[fi & 7] = -FLT_MAX;
    }
}

// ---------------------------------------------------------------------------
// K4: flash split-K attention partials + V column-sum accumulation.
// v2 scores phase: j-outer loop — K chunks and Q chunks hoisted across the
// (q,k) pair loop: 112 ds_read_b128/wave instead of 384 (3.4x less LDS).
// ---------------------------------------------------------------------------
__global__ __launch_bounds__(256) void attn_partial(
    const float* __restrict__ Qt, const float* __restrict__ Kt,
    const float* __restrict__ Vt, const int* __restrict__ topidx,
    float* __restrict__ psums, float* __restrict__ pacc,
    float* __restrict__ VmeanRaw)
{
    const int bh = blockIdx.x;
    const int c  = blockIdx.y;
    const int kbase = c * TK;
    const int tid = threadIdx.x;

    __shared__ float Qs[NTOP][DHD];
    __shared__ float Ks[TK][68];
    __shared__ float Vs[TK][68];
    __shared__ float Sc[TK][52];

    for (int i = tid; i < NTOP * DHD; i += 256) {
        const int q = i >> 6, d = i & 63;
        const int row = topidx[bh * NTOP + q];
        Qs[q][d] = Qt[((size_t)bh * LSEQ + row) * DHD + d];
    }
    {
        const int r0 = tid >> 4, c4 = tid & 15;
#pragma unroll
        for (int rr = 0; rr < 4; ++rr) {
            const int r = r0 + rr * 16;
            const size_t g = ((size_t)bh * LSEQ + kbase + r) * DHD + c4 * 4;
            *reinterpret_cast<float4*>(&Ks[r][c4 * 4]) =
                *reinterpret_cast<const float4*>(Kt + g);
            *reinterpret_cast<float4*>(&Vs[r][c4 * 4]) =
                *reinterpret_cast<const float4*>(Vt + g);
        }
    }
    __syncthreads();

    {
        const int d = tid & 63, part = tid >> 6;
        float s = 0.f;
#pragma unroll
        for (int i = 0; i < 16; ++i) s += Vs[part * 16 + i][d];
        atomicAdd(&VmeanRaw[bh * DHD + d], s);
    }

    // scores, j-outer: thread = (kloc = tid&15, qg = tid>>4)
    {
        const int kloc = tid & 15, qg = tid >> 4;
        float accp[3][4] = {};
        const int q2 = (qg < 8) ? qg + 32 : qg;    // clamped; unused if qg>=8
#pragma unroll
        for (int j = 0; j < 16; ++j) {
            const float4 kv[4] = {
                *reinterpret_cast<const float4*>(&Ks[kloc     ][j * 4]),
                *reinterpret_cast<const float4*>(&Ks[kloc + 16][j * 4]),
                *reinterpret_cast<const float4*>(&Ks[kloc + 32][j * 4]),
                *reinterpret_cast<const float4*>(&Ks[kloc + 48][j * 4])};
            const float4 qv[3] = {
                *reinterpret_cast<const float4*>(&Qs[qg     ][j * 4]),
                *reinterpret_cast<const float4*>(&Qs[qg + 16][j * 4]),
                *reinterpret_cast<const float4*>(&Qs[q2     ][j * 4])};
#pragma unroll
            for (int qi = 0; qi < 3; ++qi)
#pragma unroll
                for (int kb = 0; kb < 4; ++kb)
                    accp[qi][kb] += qv[qi].x * kv[kb].x + qv[qi].y * kv[kb].y +
                                    qv[qi].z * kv[kb].z + qv[qi].w * kv[kb].w;
        }
#pragma unroll
        for (int qi = 0; qi < 3; ++qi) {
            const int q = qg + qi * 16;
            if (q < NTOP) {
#pragma unroll
                for (int kb = 0; kb < 4; ++kb)
                    Sc[kloc + kb * 16][q] = accp[qi][kb] * QK_SCALE;
            }
        }
    }
    __syncthreads();

    {
        const int w = tid >> 6, lane = tid & 63;
#pragma unroll
        for (int j = 0; j < 10; ++j) {
            const int q = w * 10 + j;
            const float ee = __expf(Sc[lane][q]);
            float s = ee;
#pragma unroll
            for (int off = 32; off; off >>= 1) s += __shfl_xor(s, off);
            Sc[lane][q] = ee;
            if (lane == 0) psums[((size_t)bh * NCHUNK + c) * NTOP + q] = s;
        }
    }
    __syncthreads();

    {
        const int d = tid & 63, g = tid >> 6;
        const int q0 = g * 12;
        const int nq = (g < 3) ? 12 : 4;
        float acc[12] = {};
        for (int k = 0; k < TK; ++k) {
            const float v = Vs[k][d];
            const float4 s0 = *reinterpret_cast<const float4*>(&Sc[k][q0]);
            acc[0] = fmaf(s0.x, v, acc[0]); acc[1] = fmaf(s0.y, v, acc[1]);
            acc[2] = fmaf(s0.z, v, acc[2]); acc[3] = fmaf(s0.w, v, acc[3]);
            if (g < 3) {
                const float4 s1 = *reinterpret_cast<const float4*>(&Sc[k][q0 + 4]);
                const float4 s2 = *reinterpret_cast<const float4*>(&Sc[k][q0 + 8]);
                acc[4] = fmaf(s1.x, v, acc[4]); acc[5]  = fmaf(s1.y, v, acc[5]);
                acc[6] = fmaf(s1.z, v, acc[6]); acc[7]  = fmaf(s1.w, v, acc[7]);
                acc[8] = fmaf(s2.x, v, acc[8]); acc[9]  = fmaf(s2.y, v, acc[9]);
                acc[10] = fmaf(s2.z, v, acc[10]); acc[11] = fmaf(s2.w, v, acc[11]);
            }
        }
#pragma unroll
        for (int j = 0; j < 12; ++j)
            if (j < nq)
                pacc[(((size_t)bh * NCHUNK + c) * NTOP + q0 + j) * DHD + d] = acc[j];
    }
}

// ---------------------------------------------------------------------------
// K5: combine partials -> delta; grid (32 bh, 4 q-quarters). y==0 & bh%8==0
// blocks also compute meanout.
// ---------------------------------------------------------------------------
__global__ __launch_bounds__(256) void attn_combine(
    const float* __restrict__ psums, const float* __restrict__ pacc,
    const float* __restrict__ VmeanRaw, const float* __restrict__ Wo,
    const float* __restrict__ bo, float* __restrict__ delta,
    float* __restrict__ meanout)
{
    const int bh = blockIdx.x;
    const int y  = blockIdx.y;
    __shared__ float winv[10];
    __shared__ float mc[DMODEL];
    if (threadIdx.x < 10) {
        const int q = y * 10 + threadIdx.x;
        float s = 0.f;
        for (int c = 0; c < NCHUNK; ++c)
            s += psums[((size_t)bh * NCHUNK + c) * NTOP + q];
        winv[threadIdx.x] = 1.0f / s;
    }
    __syncthreads();
    const int d = threadIdx.x & 63, g = threadIdx.x >> 6;
    const float vm = VmeanRaw[bh * DHD + d] * (1.0f / (float)LSEQ);
    for (int q = y * 10 + g; q < y * 10 + 10; q += 4) {
        float a = 0.f;
        for (int c = 0; c < NCHUNK; ++c)
            a += pacc[(((size_t)bh * NCHUNK + c) * NTOP + q) * DHD + d];
        delta[((size_t)bh * NTOP + q) * DHD + d] = a * winv[q - y * 10] - vm;
    }

    if (y == 0 && (bh & 7) == 0) {
        const int b = bh >> 3;
        for (int i = threadIdx.x; i < DMODEL; i += 256)
            mc[i] = VmeanRaw[b * DMODEL + i] * (1.0f / (float)LSEQ);
        __syncthreads();
        for (int n = threadIdx.x; n < DMODEL; n += 256) {
            float acc = bo[n];
            const float* wr = Wo + (size_t)n * DMODEL;
            for (int k = 0; k < DMODEL; ++k) acc = fmaf(mc[k], wr[k], acc);
            meanout[b * DMODEL + n] = acc;
        }
    }
}

// ---------------------------------------------------------------------------
// K6: final output rows; 128 threads, float4 path.
// ---------------------------------------------------------------------------
__global__ __launch_bounds__(128) void out_kernel(
    const float* __restrict__ meanout, const unsigned* __restrict__ headmask,
    const unsigned char* __restrict__ slot, const float* __restrict__ delta,
    const float* __restrict__ Wo, float* __restrict__ out)
{
    const int rowg = blockIdx.x;
    const int b = rowg >> 11, lloc = rowg & (LSEQ - 1);
    const unsigned mask = headmask[rowg];

    __shared__ float dl[NH][DHD];
    if (threadIdx.x < DHD) {
        for (int h = 0; h < NH; ++h) {
            if ((mask >> h) & 1) {
                const int bh = b * NH + h;
                const int u = slot[bh * LSEQ + lloc];
                dl[h][threadIdx.x] = delta[((size_t)bh * NTOP + u) * DHD + threadIdx.x];
            }
        }
    }
    __syncthreads();

    const int n4 = threadIdx.x;
    float4 val = *reinterpret_cast<const float4*>(meanout + b * DMODEL + n4 * 4);
    unsigned mm = mask;
    while (mm) {
        const int h = __ffs(mm) - 1;
        mm &= mm - 1;
#pragma unroll
        for (int c = 0; c < 4; ++c) {
            const int n = n4 * 4 + c;
            const float4* wr4 = reinterpret_cast<const float4*>(
                Wo + (size_t)n * DMODEL + h * DHD);
            float a = 0.f;
#pragma unroll
            for (int dd = 0; dd < 16; ++dd) {
                const float4 wv = wr4[dd];
                a += dl[h][dd * 4 + 0] * wv.x + dl[h][dd * 4 + 1] * wv.y +
                     dl[h][dd * 4 + 2] * wv.z + dl[h][dd * 4 + 3] * wv.w;
            }
            (&val.x)[c] += a;
        }
    }
    *reinterpret_cast<float4*>(out + (size_t)rowg * DMODEL + n4 * 4) = val;
}

// ---------------------------------------------------------------------------
extern "C" void kernel_launch(void* const* d_in, const int* in_sizes, int n_in,
                              void* d_out, int out_size, void* d_ws, size_t ws_size,
                              hipStream_t stream)
{
    (void)in_sizes; (void)n_in; (void)out_size; (void)ws_size;
    const float* x     = (const float*)d_in[0];
    const float* ctxin = (const float*)d_in[1];
    const float* Wq    = (const float*)d_in[2];
    const float* bq    = (const float*)d_in[3];
    const float* Wk    = (const float*)d_in[4];
    const float* bk    = (const float*)d_in[5];
    const float* Wv    = (const float*)d_in[6];
    const float* bv    = (const float*)d_in[7];
    const float* Wo    = (const float*)d_in[8];
    const float* bo    = (const float*)d_in[9];
    const int*   idxs  = (const int*)d_in[10];
    float* out = (float*)d_out;

    char* ws = (char*)d_ws;
    size_t off = 0;
    auto alloc = [&](size_t bytes) -> void* {
        void* p = ws + off;
        off += (bytes + 255) & ~(size_t)255;
        return p;
    };

    const size_t qkv_bytes = (size_t)BATCH * NH * LSEQ * DHD * sizeof(float);
    float*         Qt       = (float*)alloc(qkv_bytes);
    float*         Kt       = (float*)alloc(qkv_bytes);
    float*         Vt       = (float*)alloc(qkv_bytes);
    float*         Mbuf     = (float*)alloc((size_t)BATCH * NH * LSEQ * sizeof(float));
    float*         VmeanRaw = (float*)alloc((size_t)BATCH * NH * DHD * sizeof(float));
    float*         meanout  = (float*)alloc((size_t)BATCH * DMODEL * sizeof(float));
    float*         delta    = (float*)alloc((size_t)BATCH * NH * NTOP * DHD * sizeof(float));
    int*           topidx   = (int*)alloc((size_t)BATCH * NH * NTOP * sizeof(int));
    unsigned*      headmask = (unsigned*)alloc((size_t)BATCH * LSEQ * sizeof(unsigned));
    unsigned char* slot     = (unsigned char*)alloc((size_t)BATCH * NH * LSEQ);
    float*         psums    = (float*)alloc((size_t)BATCH * NH * NCHUNK * NTOP * sizeof(float));
    u16*           xsP      = (u16*)alloc(ASTRIDE * 3 * 2);
    u16*           csP      = (u16*)alloc(ASTRIDE * 3 * 2);
    u16*           wqP      = (u16*)alloc(WSTRIDE * 3 * 2);
    u16*           wkP      = (u16*)alloc(WSTRIDE * 3 * 2);
    u16*           wvP      = (u16*)alloc(WSTRIDE * 3 * 2);
    // pacc (10.5 MB) aliases xsP planes: x-planes dead after the QK gemm
    // (V gemm reads csP/wvP only); attn_partial runs strictly after both.
    float*         pacc     = (float*)xsP;

    split3_all<<<2048, 256, 0, stream>>>(x, ctxin, Wq, Wk, Wv,
                                         xsP, csP, wqP, wkP, wvP);

    gemm_mfma<3><<<dim3(256, 2), 256, 0, stream>>>(
        xsP, wqP, csP, wkP, bq, bk, Qt, Kt);

    gemm_mfma<2><<<dim3(256, 1), 256, 0, stream>>>(
        csP, wvP, csP, wvP, bv, bv, Vt, Vt);

    score_kernel<<<(BATCH * NH * LSEQ) / 4, 256, 0, stream>>>(
        Qt, Kt, idxs, Mbuf, headmask, VmeanRaw);

    topk_kernel<<<BATCH * NH, 256, 0, stream>>>(Mbuf, topidx, headmask, slot);

    attn_partial<<<dim3(BATCH * NH, NCHUNK), 256, 0, stream>>>(
        Qt, Kt, Vt, topidx, psums, pacc, VmeanRaw);

    attn_combine<<<dim3(BATCH * NH, 4), 256, 0, stream>>>(
        psums, pacc, VmeanRaw, Wo, bo, delta, meanout);

    out_kernel<<<BATCH * LSEQ, 128, 0, stream>>>(
        meanout, headmask, slot, delta, Wo, out);
}

// Round 12
// 295.228 us; speedup vs baseline: 1.1203x; 1.1203x over previous
//
#include <hip/hip_runtime.h>
#include <float.h>

#define BATCH 4
#define LSEQ  2048
#define DMODEL 512
#define NH    8
#define DHD   64
#define NSAMP 40
#define NTOP  40
#define NCHUNK 64
#define TK    32
#define QK_SCALE 0.125f

typedef unsigned short u16;
typedef __attribute__((ext_vector_type(8))) short short8b;  // 8 bf16 = 16 B
typedef __attribute__((ext_vector_type(4))) float f32x4;
typedef __attribute__((ext_vector_type(4))) float f32x4v;

#define ASTRIDE ((size_t)BATCH * LSEQ * DMODEL)   // 4,194,304 elems (2^22)
#define WSTRIDE ((size_t)DMODEL * DMODEL)         //   262,144 elems (2^18)

// RTNE float->bf16 on raw bits (inputs finite).
static __device__ __forceinline__ u16 f2bf(float x) {
    unsigned u = __float_as_uint(x);
    u += 0x7FFFu + ((u >> 16) & 1u);
    return (u16)(u >> 16);
}
static __device__ __forceinline__ float bf2f(u16 s) {
    return __uint_as_float((unsigned)s << 16);
}

// ---------------------------------------------------------------------------
// K0: unified 3-way bf16 split, ONE dispatch. x = p1+p2+p3 + O(2^-27|x|).
// ---------------------------------------------------------------------------
__global__ __launch_bounds__(256) void split3_all(
    const float* __restrict__ x, const float* __restrict__ ctxin,
    const float* __restrict__ Wq, const float* __restrict__ Wk,
    const float* __restrict__ Wv,
    u16* __restrict__ xsP, u16* __restrict__ csP,
    u16* __restrict__ wqP, u16* __restrict__ wkP, u16* __restrict__ wvP)
{
    const int X4 = 1 << 20;
    const int W4 = 1 << 16;
    const int total = 2 * X4 + 3 * W4;
    for (int i = blockIdx.x * 256 + threadIdx.x; i < total; i += gridDim.x * 256) {
        const float* src; u16* dst; size_t pstride; int i4;
        if (i < X4)            { src = x;     dst = xsP; pstride = ASTRIDE; i4 = i; }
        else if (i < 2 * X4)   { src = ctxin; dst = csP; pstride = ASTRIDE; i4 = i - X4; }
        else {
            const int w = i - 2 * X4;
            const int which = w >> 16, rem = w & (W4 - 1);
            src = (which == 0) ? Wq : (which == 1) ? Wk : Wv;
            dst = (which == 0) ? wqP : (which == 1) ? wkP : wvP;
            pstride = WSTRIDE; i4 = rem;
        }
        const float4 v = reinterpret_cast<const float4*>(src)[i4];
        const float in[4] = {v.x, v.y, v.z, v.w};
        ushort4 o1, o2, o3;
        u16 b1[4], b2[4], b3[4];
#pragma unroll
        for (int c = 0; c < 4; ++c) {
            const float xx = in[c];
            b1[c] = f2bf(xx);
            const float r1 = xx - bf2f(b1[c]);
            b2[c] = f2bf(r1);
            b3[c] = f2bf(r1 - bf2f(b2[c]));
        }
        o1.x = b1[0]; o1.y = b1[1]; o1.z = b1[2]; o1.w = b1[3];
        o2.x = b2[0]; o2.y = b2[1]; o2.z = b2[2]; o2.w = b2[3];
        o3.x = b3[0]; o3.y = b3[1]; o3.z = b3[2]; o3.w = b3[3];
        reinterpret_cast<ushort4*>(dst)[i4]                = o1;
        reinterpret_cast<ushort4*>(dst + pstride)[i4]      = o2;
        reinterpret_cast<ushort4*>(dst + 2 * pstride)[i4]  = o3;
    }
}

// ---------------------------------------------------------------------------
// K1: GEMM on MFMA, bf16xNP planes. NP=3 (Q,K): fp32-accuracy 6-product.
// NP=2 (V): 3-product, err ~1e-5 (V never feeds top-k). Tile 128x128.
// ---------------------------------------------------------------------------
template<int NP>
__global__ __launch_bounds__(256) void gemm_mfma(
    const u16* __restrict__ A0, const u16* __restrict__ W0,
    const u16* __restrict__ A1, const u16* __restrict__ W1,
    const float* __restrict__ bias0, const float* __restrict__ bias1,
    float* __restrict__ Out0, float* __restrict__ Out1)
{
    const int z = blockIdx.y;
    const int i = blockIdx.x;
    const int xcd = i & 7;
    const int loc = i >> 3;
    const int m0 = (xcd * 8 + (loc & 7)) * 128;
    const int n0 = (loc >> 3) * 128;

    const u16* __restrict__ Ap   = z ? A1 : A0;
    const u16* __restrict__ Wp   = z ? W1 : W0;
    const float* __restrict__ bias = z ? bias1 : bias0;
    float*       __restrict__ Out  = z ? Out1 : Out0;

    __shared__ u16 As[NP][128][40];
    __shared__ u16 Ws[NP][128][40];

    const int tid  = threadIdx.x;
    const int w    = tid >> 6;
    const int lane = tid & 63;
    const int wm   = w >> 1;
    const int wn   = w & 1;
    const int lr   = lane & 15;
    const int lg   = lane >> 4;

    const int srow = tid >> 1;
    const int sc   = (tid & 1) * 16;

    f32x4 acc[4][4];
#pragma unroll
    for (int mf = 0; mf < 4; ++mf)
#pragma unroll
        for (int nf = 0; nf < 4; ++nf)
#pragma unroll
            for (int r = 0; r < 4; ++r) acc[mf][nf][r] = 0.f;

    short8b sa[NP][2], sw[NP][2];
#pragma unroll
    for (int p = 0; p < NP; ++p) {
        const u16* asrc = Ap + p * ASTRIDE + (size_t)(m0 + srow) * DMODEL + sc;
        const u16* wsrc = Wp + p * WSTRIDE + (size_t)(n0 + srow) * DMODEL + sc;
        sa[p][0] = *reinterpret_cast<const short8b*>(asrc);
        sa[p][1] = *reinterpret_cast<const short8b*>(asrc + 8);
        sw[p][0] = *reinterpret_cast<const short8b*>(wsrc);
        sw[p][1] = *reinterpret_cast<const short8b*>(wsrc + 8);
    }

    for (int k0 = 0; k0 < DMODEL; k0 += 32) {
#pragma unroll
        for (int p = 0; p < NP; ++p) {
            *reinterpret_cast<short8b*>(&As[p][srow][sc])     = sa[p][0];
            *reinterpret_cast<short8b*>(&As[p][srow][sc + 8]) = sa[p][1];
            *reinterpret_cast<short8b*>(&Ws[p][srow][sc])     = sw[p][0];
            *reinterpret_cast<short8b*>(&Ws[p][srow][sc + 8]) = sw[p][1];
        }
        __syncthreads();

        if (k0 + 32 < DMODEL) {
#pragma unroll
            for (int p = 0; p < NP; ++p) {
                const u16* asrc =
                    Ap + p * ASTRIDE + (size_t)(m0 + srow) * DMODEL + k0 + 32 + sc;
                const u16* wsrc =
                    Wp + p * WSTRIDE + (size_t)(n0 + srow) * DMODEL + k0 + 32 + sc;
                sa[p][0] = *reinterpret_cast<const short8b*>(asrc);
                sa[p][1] = *reinterpret_cast<const short8b*>(asrc + 8);
                sw[p][0] = *reinterpret_cast<const short8b*>(wsrc);
                sw[p][1] = *reinterpret_cast<const short8b*>(wsrc + 8);
            }
        }

        short8b af[4][NP];
#pragma unroll
        for (int mf = 0; mf < 4; ++mf) {
            const int row = wm * 64 + mf * 16 + lr;
#pragma unroll
            for (int p = 0; p < NP; ++p)
                af[mf][p] = *reinterpret_cast<const short8b*>(&As[p][row][lg * 8]);
        }
#pragma unroll
        for (int nf = 0; nf < 4; ++nf) {
            const int row = wn * 64 + nf * 16 + lr;
            const short8b b1 = *reinterpret_cast<const short8b*>(&Ws[0][row][lg * 8]);
            const short8b b2 = *reinterpret_cast<const short8b*>(&Ws[1][row][lg * 8]);
#pragma unroll
            for (int mf = 0; mf < 4; ++mf) {
                acc[mf][nf] = __builtin_amdgcn_mfma_f32_16x16x32_bf16(af[mf][0], b1, acc[mf][nf], 0, 0, 0);
                acc[mf][nf] = __builtin_amdgcn_mfma_f32_16x16x32_bf16(af[mf][1], b1, acc[mf][nf], 0, 0, 0);
                acc[mf][nf] = __builtin_amdgcn_mfma_f32_16x16x32_bf16(af[mf][0], b2, acc[mf][nf], 0, 0, 0);
                if constexpr (NP == 3) {
                    const short8b b3 = *reinterpret_cast<const short8b*>(&Ws[2][row][lg * 8]);
                    acc[mf][nf] = __builtin_amdgcn_mfma_f32_16x16x32_bf16(af[mf][2], b1, acc[mf][nf], 0, 0, 0);
                    acc[mf][nf] = __builtin_amdgcn_mfma_f32_16x16x32_bf16(af[mf][0], b3, acc[mf][nf], 0, 0, 0);
                    acc[mf][nf] = __builtin_amdgcn_mfma_f32_16x16x32_bf16(af[mf][1], b2, acc[mf][nf], 0, 0, 0);
                }
            }
        }
        __syncthreads();
    }

#pragma unroll
    for (int nf = 0; nf < 4; ++nf) {
        const int n = n0 + wn * 64 + nf * 16 + lr;
        const int h = n >> 6, d = n & 63;
        const float bv_ = bias[n];
#pragma unroll
        for (int mf = 0; mf < 4; ++mf) {
#pragma unroll
            for (int r = 0; r < 4; ++r) {
                const int m = m0 + wm * 64 + mf * 16 + lg * 4 + r;
                const int b = m >> 11, l = m & (LSEQ - 1);
                Out[((size_t)(b * NH + h) * LSEQ + l) * DHD + d] = acc[mf][nf][r] + bv_;
            }
        }
    }
}

// ---------------------------------------------------------------------------
// K2: sampled sparsity measure + zero-init of headmask/VmeanRaw.
// ---------------------------------------------------------------------------
__global__ __launch_bounds__(256) void score_kernel(
    const float* __restrict__ Qt, const float* __restrict__ Kt,
    const int* __restrict__ idxs, float* __restrict__ M,
    unsigned* __restrict__ headmask, float* __restrict__ VmeanRaw)
{
    const int flat = blockIdx.x;
    if (flat < 32) headmask[flat * 256 + threadIdx.x] = 0u;
    else if (flat < 40) VmeanRaw[(flat - 32) * 256 + threadIdx.x] = 0.f;

    const int xcd  = flat & 7;
    const int slot = flat >> 3;
    const int bh   = xcd * 4 + (slot >> 9);
    const int w    = threadIdx.x >> 6;
    const int lane = threadIdx.x & 63;
    const int l    = (slot & 511) * 4 + w;

    const int g  = lane >> 4;
    const int dl = lane & 15;

#if defined(__has_builtin) && __has_builtin(__builtin_nontemporal_load)
    const f32x4v q4 = __builtin_nontemporal_load(
        reinterpret_cast<const f32x4v*>(Qt + ((size_t)bh * LSEQ + l) * DHD + dl * 4));
#else
    const f32x4v q4 = *reinterpret_cast<const f32x4v*>(
        Qt + ((size_t)bh * LSEQ + l) * DHD + dl * 4);
#endif

    const float* Kb = Kt + (size_t)bh * LSEQ * DHD;
    float vmax = -FLT_MAX, vsum = 0.f;
#pragma unroll
    for (int it = 0; it < 10; ++it) {
        const int s = it * 4 + g;
        const int ks = idxs[l * NSAMP + s];
        const float4 k4 = *reinterpret_cast<const float4*>(
            Kb + (size_t)ks * DHD + dl * 4);
        float p = q4[0] * k4.x + q4[1] * k4.y + q4[2] * k4.z + q4[3] * k4.w;
        p += __shfl_xor(p, 1);
        p += __shfl_xor(p, 2);
        p += __shfl_xor(p, 4);
        p += __shfl_xor(p, 8);
        vmax = fmaxf(vmax, p);
        vsum += p;
    }
    vmax = fmaxf(vmax, __shfl_xor(vmax, 16));
    vsum += __shfl_xor(vsum, 16);
    vmax = fmaxf(vmax, __shfl_xor(vmax, 32));
    vsum += __shfl_xor(vsum, 32);
    if (lane == 0) M[(size_t)bh * LSEQ + l] = vmax - vsum * (1.0f / LSEQ);
}

// ---------------------------------------------------------------------------
// K3: stable top-40 per (b,h); candidates in registers.
// ---------------------------------------------------------------------------
__global__ __launch_bounds__(256) void topk_kernel(
    const float* __restrict__ M, int* __restrict__ topidx,
    unsigned* __restrict__ headmask, unsigned char* __restrict__ slot)
{
    const int bh = blockIdx.x;
    const int b = bh >> 3, h = bh & 7;
    const int w = threadIdx.x >> 6, lane = threadIdx.x & 63;
    const int base = threadIdx.x * 8;

    float e[8];
    {
        const float4 v0 = *reinterpret_cast<const float4*>(M + (size_t)bh * LSEQ + base);
        const float4 v1 = *reinterpret_cast<const float4*>(M + (size_t)bh * LSEQ + base + 4);
        e[0] = v0.x; e[1] = v0.y; e[2] = v0.z; e[3] = v0.w;
        e[4] = v1.x; e[5] = v1.y; e[6] = v1.z; e[7] = v1.w;
    }

    __shared__ float rv[4];
    __shared__ int   ri[4];
    __shared__ int   winner;

    for (int t = 0; t < NTOP; ++t) {
        float bv = e[0]; int br = 0;
#pragma unroll
        for (int r = 1; r < 8; ++r)
            if (e[r] > bv) { bv = e[r]; br = r; }
        int bi = base + br;
#pragma unroll
        for (int off = 32; off; off >>= 1) {
            const float ov = __shfl_xor(bv, off);
            const int   oi = __shfl_xor(bi, off);
            if (ov > bv || (ov == bv && oi < bi)) { bv = ov; bi = oi; }
        }
        if (lane == 0) { rv[w] = bv; ri[w] = bi; }
        __syncthreads();
        if (threadIdx.x == 0) {
            float fv = rv[0]; int fi = ri[0];
#pragma unroll
            for (int k = 1; k < 4; ++k)
                if (rv[k] > fv || (rv[k] == fv && ri[k] < fi)) { fv = rv[k]; fi = ri[k]; }
            topidx[bh * NTOP + t] = fi;
            atomicOr(&headmask[b * LSEQ + fi], 1u << h);
            slot[bh * LSEQ + fi] = (unsigned char)t;
            winner = fi;
        }
        __syncthreads();
        const int fi = winner;
        if ((fi >> 3) == threadIdx.x) e[fi & 7] = -FLT_MAX;
    }
}

// ---------------------------------------------------------------------------
// K4: flash split-K attention partials + V column-sum accumulation.
// v3: TK=32 (LDS 34 KB -> 4 blocks/CU, was 2), round-10-style scores phase
// (j-outer reverted: it cost VGPR 116->232 and 10% occupancy).
// ---------------------------------------------------------------------------
__global__ __launch_bounds__(256) void attn_partial(
    const float* __restrict__ Qt, const float* __restrict__ Kt,
    const float* __restrict__ Vt, const int* __restrict__ topidx,
    float* __restrict__ psums, float* __restrict__ pacc,
    float* __restrict__ VmeanRaw)
{
    const int bh = blockIdx.x;
    const int c  = blockIdx.y;
    const int kbase = c * TK;
    const int tid = threadIdx.x;

    __shared__ float Qs[NTOP][DHD];      // 10240 B
    __shared__ float Ks[TK][68];         //  8704 B
    __shared__ float Vs[TK][68];         //  8704 B
    __shared__ float Sc[TK][52];         //  6656 B  -> total 34304 B

    for (int i = tid; i < NTOP * DHD; i += 256) {
        const int q = i >> 6, d = i & 63;
        const int row = topidx[bh * NTOP + q];
        Qs[q][d] = Qt[((size_t)bh * LSEQ + row) * DHD + d];
    }
    {
        const int r0 = tid >> 4, c4 = tid & 15;
#pragma unroll
        for (int rr = 0; rr < 2; ++rr) {
            const int r = r0 + rr * 16;
            const size_t g = ((size_t)bh * LSEQ + kbase + r) * DHD + c4 * 4;
            *reinterpret_cast<float4*>(&Ks[r][c4 * 4]) =
                *reinterpret_cast<const float4*>(Kt + g);
            *reinterpret_cast<float4*>(&Vs[r][c4 * 4]) =
                *reinterpret_cast<const float4*>(Vt + g);
        }
    }
    __syncthreads();

    // V column partial sums (vmean fold-in)
    {
        const int d = tid & 63, part = tid >> 6;
        float s = 0.f;
#pragma unroll
        for (int i = 0; i < 8; ++i) s += Vs[part * 8 + i][d];
        atomicAdd(&VmeanRaw[bh * DHD + d], s);
    }

    // scores: thread -> (kloc = tid&15, qg = tid>>4); k = kloc + kb*16, kb<2
    {
        const int kloc = tid & 15, qg = tid >> 4;
#pragma unroll
        for (int qit = 0; qit < 3; ++qit) {
            const int q = qg + qit * 16;
            if (q < NTOP) {
#pragma unroll
                for (int kb = 0; kb < 2; ++kb) {
                    const int k = kloc + kb * 16;
                    float acc = 0.f;
#pragma unroll
                    for (int j = 0; j < 16; ++j) {
                        const float4 kv = *reinterpret_cast<const float4*>(&Ks[k][j * 4]);
                        const float4 qv = *reinterpret_cast<const float4*>(&Qs[q][j * 4]);
                        acc += qv.x * kv.x + qv.y * kv.y + qv.z * kv.z + qv.w * kv.w;
                    }
                    Sc[k][q] = acc * QK_SCALE;
                }
            }
        }
    }
    __syncthreads();

    // exp + per-chunk partial sums (lane&31 -> k; both wave halves redundant)
    {
        const int w = tid >> 6, lane = tid & 63;
        const int k = lane & 31;
#pragma unroll
        for (int j = 0; j < 10; ++j) {
            const int q = w * 10 + j;
            const float ee = __expf(Sc[k][q]);
            float s = ee;
            s += __shfl_xor(s, 1);
            s += __shfl_xor(s, 2);
            s += __shfl_xor(s, 4);
            s += __shfl_xor(s, 8);
            s += __shfl_xor(s, 16);
            if (lane < 32) Sc[k][q] = ee;
            if (lane == 0) psums[((size_t)bh * NCHUNK + c) * NTOP + q] = s;
        }
    }
    __syncthreads();

    // partial PV
    {
        const int d = tid & 63, g = tid >> 6;
        const int q0 = g * 12;
        const int nq = (g < 3) ? 12 : 4;
        float acc[12] = {};
        for (int k = 0; k < TK; ++k) {
            const float v = Vs[k][d];
            const float4 s0 = *reinterpret_cast<const float4*>(&Sc[k][q0]);
            acc[0] = fmaf(s0.x, v, acc[0]); acc[1] = fmaf(s0.y, v, acc[1]);
            acc[2] = fmaf(s0.z, v, acc[2]); acc[3] = fmaf(s0.w, v, acc[3]);
            if (g < 3) {
                const float4 s1 = *reinterpret_cast<const float4*>(&Sc[k][q0 + 4]);
                const float4 s2 = *reinterpret_cast<const float4*>(&Sc[k][q0 + 8]);
                acc[4] = fmaf(s1.x, v, acc[4]); acc[5]  = fmaf(s1.y, v, acc[5]);
                acc[6] = fmaf(s1.z, v, acc[6]); acc[7]  = fmaf(s1.w, v, acc[7]);
                acc[8] = fmaf(s2.x, v, acc[8]); acc[9]  = fmaf(s2.y, v, acc[9]);
                acc[10] = fmaf(s2.z, v, acc[10]); acc[11] = fmaf(s2.w, v, acc[11]);
            }
        }
#pragma unroll
        for (int j = 0; j < 12; ++j)
            if (j < nq)
                pacc[(((size_t)bh * NCHUNK + c) * NTOP + q0 + j) * DHD + d] = acc[j];
    }
}

// ---------------------------------------------------------------------------
// K5: combine partials -> delta; grid (32 bh, 4 q-quarters). y==0 & bh%8==0
// blocks also compute meanout.
// ---------------------------------------------------------------------------
__global__ __launch_bounds__(256) void attn_combine(
    const float* __restrict__ psums, const float* __restrict__ pacc,
    const float* __restrict__ VmeanRaw, const float* __restrict__ Wo,
    const float* __restrict__ bo, float* __restrict__ delta,
    float* __restrict__ meanout)
{
    const int bh = blockIdx.x;
    const int y  = blockIdx.y;
    __shared__ float winv[10];
    __shared__ float mc[DMODEL];
    if (threadIdx.x < 10) {
        const int q = y * 10 + threadIdx.x;
        float s = 0.f;
        for (int c = 0; c < NCHUNK; ++c)
            s += psums[((size_t)bh * NCHUNK + c) * NTOP + q];
        winv[threadIdx.x] = 1.0f / s;
    }
    __syncthreads();
    const int d = threadIdx.x & 63, g = threadIdx.x >> 6;
    const float vm = VmeanRaw[bh * DHD + d] * (1.0f / (float)LSEQ);
    for (int q = y * 10 + g; q < y * 10 + 10; q += 4) {
        float a = 0.f;
        for (int c = 0; c < NCHUNK; ++c)
            a += pacc[(((size_t)bh * NCHUNK + c) * NTOP + q) * DHD + d];
        delta[((size_t)bh * NTOP + q) * DHD + d] = a * winv[q - y * 10] - vm;
    }

    if (y == 0 && (bh & 7) == 0) {
        const int b = bh >> 3;
        for (int i = threadIdx.x; i < DMODEL; i += 256)
            mc[i] = VmeanRaw[b * DMODEL + i] * (1.0f / (float)LSEQ);
        __syncthreads();
        for (int n = threadIdx.x; n < DMODEL; n += 256) {
            float acc = bo[n];
            const float* wr = Wo + (size_t)n * DMODEL;
            for (int k = 0; k < DMODEL; ++k) acc = fmaf(mc[k], wr[k], acc);
            meanout[b * DMODEL + n] = acc;
        }
    }
}

// ---------------------------------------------------------------------------
// K6a: broadcast mean rows to ALL output rows (pure streaming write).
// ---------------------------------------------------------------------------
__global__ __launch_bounds__(256) void out_base(
    const float* __restrict__ meanout, float* __restrict__ out)
{
    const int total4 = BATCH * LSEQ * (DMODEL / 4);   // 2^20
    for (int i = blockIdx.x * 256 + threadIdx.x; i < total4; i += gridDim.x * 256) {
        const int row = i >> 7;            // /128
        const int b = row >> 11;
        const int c = i & 127;
        reinterpret_cast<float4*>(out)[i] =
            reinterpret_cast<const float4*>(meanout)[b * 128 + c];
    }
}

// ---------------------------------------------------------------------------
// K6b: scatter-add the selected rows: out[b,l,:] += delta[bh,u] @ Wo_h^T.
// One block per (bh,u); Wo (1 MB) L2-resident. atomicAdd handles rows
// selected by multiple heads (fp ordering noise ~1e-7 << threshold).
// ---------------------------------------------------------------------------
__global__ __launch_bounds__(128) void out_scatter(
    const int* __restrict__ topidx, const float* __restrict__ delta,
    const float* __restrict__ Wo, float* __restrict__ out)
{
    const int bh = blockIdx.x;
    const int u  = blockIdx.y;
    const int b = bh >> 3, h = bh & 7;
    const int l = topidx[bh * NTOP + u];

    __shared__ float dl[DHD];
    if (threadIdx.x < DHD)
        dl[threadIdx.x] = delta[((size_t)bh * NTOP + u) * DHD + threadIdx.x];
    __syncthreads();

    float* orow = out + ((size_t)b * LSEQ + l) * DMODEL;
#pragma unroll
    for (int c = 0; c < 4; ++c) {
        const int n = threadIdx.x * 4 + c;
        const float4* wr4 = reinterpret_cast<const float4*>(
            Wo + (size_t)n * DMODEL + h * DHD);
        float a = 0.f;
#pragma unroll
        for (int dd = 0; dd < 16; ++dd) {
            const float4 wv = wr4[dd];
            a += dl[dd * 4 + 0] * wv.x + dl[dd * 4 + 1] * wv.y +
                 dl[dd * 4 + 2] * wv.z + dl[dd * 4 + 3] * wv.w;
        }
        atomicAdd(&orow[n], a);
    }
}

// ---------------------------------------------------------------------------
extern "C" void kernel_launch(void* const* d_in, const int* in_sizes, int n_in,
                              void* d_out, int out_size, void* d_ws, size_t ws_size,
                              hipStream_t stream)
{
    (void)in_sizes; (void)n_in; (void)out_size; (void)ws_size;
    const float* x     = (const float*)d_in[0];
    const float* ctxin = (const float*)d_in[1];
    const float* Wq    = (const float*)d_in[2];
    const float* bq    = (const float*)d_in[3];
    const float* Wk    = (const float*)d_in[4];
    const float* bk    = (const float*)d_in[5];
    const float* Wv    = (const float*)d_in[6];
    const float* bv    = (const float*)d_in[7];
    const float* Wo    = (const float*)d_in[8];
    const float* bo    = (const float*)d_in[9];
    const int*   idxs  = (const int*)d_in[10];
    float* out = (float*)d_out;

    char* ws = (char*)d_ws;
    size_t off = 0;
    auto alloc = [&](size_t bytes) -> void* {
        void* p = ws + off;
        off += (bytes + 255) & ~(size_t)255;
        return p;
    };

    const size_t qkv_bytes = (size_t)BATCH * NH * LSEQ * DHD * sizeof(float);
    float*         Qt       = (float*)alloc(qkv_bytes);
    float*         Kt       = (float*)alloc(qkv_bytes);
    float*         Vt       = (float*)alloc(qkv_bytes);
    float*         Mbuf     = (float*)alloc((size_t)BATCH * NH * LSEQ * sizeof(float));
    float*         VmeanRaw = (float*)alloc((size_t)BATCH * NH * DHD * sizeof(float));
    float*         meanout  = (float*)alloc((size_t)BATCH * DMODEL * sizeof(float));
    float*         delta    = (float*)alloc((size_t)BATCH * NH * NTOP * DHD * sizeof(float));
    int*           topidx   = (int*)alloc((size_t)BATCH * NH * NTOP * sizeof(int));
    unsigned*      headmask = (unsigned*)alloc((size_t)BATCH * LSEQ * sizeof(unsigned));
    unsigned char* slot     = (unsigned char*)alloc((size_t)BATCH * NH * LSEQ);
    float*         psums    = (float*)alloc((size_t)BATCH * NH * NCHUNK * NTOP * sizeof(float));
    u16*           xsP      = (u16*)alloc(ASTRIDE * 3 * 2);
    u16*           csP      = (u16*)alloc(ASTRIDE * 3 * 2);
    u16*           wqP      = (u16*)alloc(WSTRIDE * 3 * 2);
    u16*           wkP      = (u16*)alloc(WSTRIDE * 3 * 2);
    u16*           wvP      = (u16*)alloc(WSTRIDE * 3 * 2);
    // pacc (21 MB @ NCHUNK=64) aliases xsP planes (25.2 MB): x-planes dead
    // after the QK gemm; attn_partial runs strictly after both gemms.
    float*         pacc     = (float*)xsP;

    split3_all<<<2048, 256, 0, stream>>>(x, ctxin, Wq, Wk, Wv,
                                         xsP, csP, wqP, wkP, wvP);

    gemm_mfma<3><<<dim3(256, 2), 256, 0, stream>>>(
        xsP, wqP, csP, wkP, bq, bk, Qt, Kt);

    gemm_mfma<2><<<dim3(256, 1), 256, 0, stream>>>(
        csP, wvP, csP, wvP, bv, bv, Vt, Vt);

    score_kernel<<<(BATCH * NH * LSEQ) / 4, 256, 0, stream>>>(
        Qt, Kt, idxs, Mbuf, headmask, VmeanRaw);

    topk_kernel<<<BATCH * NH, 256, 0, stream>>>(Mbuf, topidx, headmask, slot);

    attn_partial<<<dim3(BATCH * NH, NCHUNK), 256, 0, stream>>>(
        Qt, Kt, Vt, topidx, psums, pacc, VmeanRaw);

    attn_combine<<<dim3(BATCH * NH, 4), 256, 0, stream>>>(
        psums, pacc, VmeanRaw, Wo, bo, delta, meanout);

    out_base<<<2048, 256, 0, stream>>>(meanout, out);

    out_scatter<<<dim3(BATCH * NH, NTOP), 128, 0, stream>>>(
        topidx, delta, Wo, out);
}

// Round 13
// 294.340 us; speedup vs baseline: 1.1236x; 1.0030x over previous
//
#include <hip/hip_runtime.h>
#include <float.h>

#define BATCH 4
#define LSEQ  2048
#define DMODEL 512
#define NH    8
#define DHD   64
#define NSAMP 40
#define NTOP  40
#define NCHUNK 64
#define TK    32
#define QK_SCALE 0.125f

typedef unsigned short u16;
typedef __attribute__((ext_vector_type(8))) short short8b;  // 8 bf16 = 16 B
typedef __attribute__((ext_vector_type(4))) float f32x4;
typedef __attribute__((ext_vector_type(4))) float f32x4v;

#define ASTRIDE ((size_t)BATCH * LSEQ * DMODEL)   // 4,194,304 elems (2^22)
#define WSTRIDE ((size_t)DMODEL * DMODEL)         //   262,144 elems (2^18)

// RTNE float->bf16 on raw bits (inputs finite).
static __device__ __forceinline__ u16 f2bf(float x) {
    unsigned u = __float_as_uint(x);
    u += 0x7FFFu + ((u >> 16) & 1u);
    return (u16)(u >> 16);
}
static __device__ __forceinline__ float bf2f(u16 s) {
    return __uint_as_float((unsigned)s << 16);
}

// ---------------------------------------------------------------------------
// K0: unified 3-way bf16 split, ONE dispatch. x = p1+p2+p3 + O(2^-27|x|).
// ---------------------------------------------------------------------------
__global__ __launch_bounds__(256) void split3_all(
    const float* __restrict__ x, const float* __restrict__ ctxin,
    const float* __restrict__ Wq, const float* __restrict__ Wk,
    const float* __restrict__ Wv,
    u16* __restrict__ xsP, u16* __restrict__ csP,
    u16* __restrict__ wqP, u16* __restrict__ wkP, u16* __restrict__ wvP)
{
    const int X4 = 1 << 20;
    const int W4 = 1 << 16;
    const int total = 2 * X4 + 3 * W4;
    for (int i = blockIdx.x * 256 + threadIdx.x; i < total; i += gridDim.x * 256) {
        const float* src; u16* dst; size_t pstride; int i4;
        if (i < X4)            { src = x;     dst = xsP; pstride = ASTRIDE; i4 = i; }
        else if (i < 2 * X4)   { src = ctxin; dst = csP; pstride = ASTRIDE; i4 = i - X4; }
        else {
            const int w = i - 2 * X4;
            const int which = w >> 16, rem = w & (W4 - 1);
            src = (which == 0) ? Wq : (which == 1) ? Wk : Wv;
            dst = (which == 0) ? wqP : (which == 1) ? wkP : wvP;
            pstride = WSTRIDE; i4 = rem;
        }
        const float4 v = reinterpret_cast<const float4*>(src)[i4];
        const float in[4] = {v.x, v.y, v.z, v.w};
        ushort4 o1, o2, o3;
        u16 b1[4], b2[4], b3[4];
#pragma unroll
        for (int c = 0; c < 4; ++c) {
            const float xx = in[c];
            b1[c] = f2bf(xx);
            const float r1 = xx - bf2f(b1[c]);
            b2[c] = f2bf(r1);
            b3[c] = f2bf(r1 - bf2f(b2[c]));
        }
        o1.x = b1[0]; o1.y = b1[1]; o1.z = b1[2]; o1.w = b1[3];
        o2.x = b2[0]; o2.y = b2[1]; o2.z = b2[2]; o2.w = b2[3];
        o3.x = b3[0]; o3.y = b3[1]; o3.z = b3[2]; o3.w = b3[3];
        reinterpret_cast<ushort4*>(dst)[i4]                = o1;
        reinterpret_cast<ushort4*>(dst + pstride)[i4]      = o2;
        reinterpret_cast<ushort4*>(dst + 2 * pstride)[i4]  = o3;
    }
}

// ---------------------------------------------------------------------------
// K1: GEMM on MFMA, bf16xNP planes. NP=3 (Q,K): fp32-accuracy 6-product.
// NP=2 (V): 3-product, err ~1e-5 (V never feeds top-k). Tile 128x128.
// ---------------------------------------------------------------------------
template<int NP>
__global__ __launch_bounds__(256) void gemm_mfma(
    const u16* __restrict__ A0, const u16* __restrict__ W0,
    const u16* __restrict__ A1, const u16* __restrict__ W1,
    const float* __restrict__ bias0, const float* __restrict__ bias1,
    float* __restrict__ Out0, float* __restrict__ Out1)
{
    const int z = blockIdx.y;
    const int i = blockIdx.x;
    const int xcd = i & 7;
    const int loc = i >> 3;
    const int m0 = (xcd * 8 + (loc & 7)) * 128;
    const int n0 = (loc >> 3) * 128;

    const u16* __restrict__ Ap   = z ? A1 : A0;
    const u16* __restrict__ Wp   = z ? W1 : W0;
    const float* __restrict__ bias = z ? bias1 : bias0;
    float*       __restrict__ Out  = z ? Out1 : Out0;

    __shared__ u16 As[NP][128][40];
    __shared__ u16 Ws[NP][128][40];

    const int tid  = threadIdx.x;
    const int w    = tid >> 6;
    const int lane = tid & 63;
    const int wm   = w >> 1;
    const int wn   = w & 1;
    const int lr   = lane & 15;
    const int lg   = lane >> 4;

    const int srow = tid >> 1;
    const int sc   = (tid & 1) * 16;

    f32x4 acc[4][4];
#pragma unroll
    for (int mf = 0; mf < 4; ++mf)
#pragma unroll
        for (int nf = 0; nf < 4; ++nf)
#pragma unroll
            for (int r = 0; r < 4; ++r) acc[mf][nf][r] = 0.f;

    short8b sa[NP][2], sw[NP][2];
#pragma unroll
    for (int p = 0; p < NP; ++p) {
        const u16* asrc = Ap + p * ASTRIDE + (size_t)(m0 + srow) * DMODEL + sc;
        const u16* wsrc = Wp + p * WSTRIDE + (size_t)(n0 + srow) * DMODEL + sc;
        sa[p][0] = *reinterpret_cast<const short8b*>(asrc);
        sa[p][1] = *reinterpret_cast<const short8b*>(asrc + 8);
        sw[p][0] = *reinterpret_cast<const short8b*>(wsrc);
        sw[p][1] = *reinterpret_cast<const short8b*>(wsrc + 8);
    }

    for (int k0 = 0; k0 < DMODEL; k0 += 32) {
#pragma unroll
        for (int p = 0; p < NP; ++p) {
            *reinterpret_cast<short8b*>(&As[p][srow][sc])     = sa[p][0];
            *reinterpret_cast<short8b*>(&As[p][srow][sc + 8]) = sa[p][1];
            *reinterpret_cast<short8b*>(&Ws[p][srow][sc])     = sw[p][0];
            *reinterpret_cast<short8b*>(&Ws[p][srow][sc + 8]) = sw[p][1];
        }
        __syncthreads();

        if (k0 + 32 < DMODEL) {
#pragma unroll
            for (int p = 0; p < NP; ++p) {
                const u16* asrc =
                    Ap + p * ASTRIDE + (size_t)(m0 + srow) * DMODEL + k0 + 32 + sc;
                const u16* wsrc =
                    Wp + p * WSTRIDE + (size_t)(n0 + srow) * DMODEL + k0 + 32 + sc;
                sa[p][0] = *reinterpret_cast<const short8b*>(asrc);
                sa[p][1] = *reinterpret_cast<const short8b*>(asrc + 8);
                sw[p][0] = *reinterpret_cast<const short8b*>(wsrc);
                sw[p][1] = *reinterpret_cast<const short8b*>(wsrc + 8);
            }
        }

        short8b af[4][NP];
#pragma unroll
        for (int mf = 0; mf < 4; ++mf) {
            const int row = wm * 64 + mf * 16 + lr;
#pragma unroll
            for (int p = 0; p < NP; ++p)
                af[mf][p] = *reinterpret_cast<const short8b*>(&As[p][row][lg * 8]);
        }
#pragma unroll
        for (int nf = 0; nf < 4; ++nf) {
            const int row = wn * 64 + nf * 16 + lr;
            const short8b b1 = *reinterpret_cast<const short8b*>(&Ws[0][row][lg * 8]);
            const short8b b2 = *reinterpret_cast<const short8b*>(&Ws[1][row][lg * 8]);
#pragma unroll
            for (int mf = 0; mf < 4; ++mf) {
                acc[mf][nf] = __builtin_amdgcn_mfma_f32_16x16x32_bf16(af[mf][0], b1, acc[mf][nf], 0, 0, 0);
                acc[mf][nf] = __builtin_amdgcn_mfma_f32_16x16x32_bf16(af[mf][1], b1, acc[mf][nf], 0, 0, 0);
                acc[mf][nf] = __builtin_amdgcn_mfma_f32_16x16x32_bf16(af[mf][0], b2, acc[mf][nf], 0, 0, 0);
                if constexpr (NP == 3) {
                    const short8b b3 = *reinterpret_cast<const short8b*>(&Ws[2][row][lg * 8]);
                    acc[mf][nf] = __builtin_amdgcn_mfma_f32_16x16x32_bf16(af[mf][2], b1, acc[mf][nf], 0, 0, 0);
                    acc[mf][nf] = __builtin_amdgcn_mfma_f32_16x16x32_bf16(af[mf][0], b3, acc[mf][nf], 0, 0, 0);
                    acc[mf][nf] = __builtin_amdgcn_mfma_f32_16x16x32_bf16(af[mf][1], b2, acc[mf][nf], 0, 0, 0);
                }
            }
        }
        __syncthreads();
    }

#pragma unroll
    for (int nf = 0; nf < 4; ++nf) {
        const int n = n0 + wn * 64 + nf * 16 + lr;
        const int h = n >> 6, d = n & 63;
        const float bv_ = bias[n];
#pragma unroll
        for (int mf = 0; mf < 4; ++mf) {
#pragma unroll
            for (int r = 0; r < 4; ++r) {
                const int m = m0 + wm * 64 + mf * 16 + lg * 4 + r;
                const int b = m >> 11, l = m & (LSEQ - 1);
                Out[((size_t)(b * NH + h) * LSEQ + l) * DHD + d] = acc[mf][nf][r] + bv_;
            }
        }
    }
}

// ---------------------------------------------------------------------------
// K2: sampled sparsity measure + zero-init of headmask/VmeanRaw/uacc/wsum.
// ---------------------------------------------------------------------------
__global__ __launch_bounds__(256) void score_kernel(
    const float* __restrict__ Qt, const float* __restrict__ Kt,
    const int* __restrict__ idxs, float* __restrict__ M,
    unsigned* __restrict__ headmask, float* __restrict__ VmeanRaw,
    float* __restrict__ uacc, float* __restrict__ wsum)
{
    const int flat = blockIdx.x;
    if (flat < 32)        headmask[flat * 256 + threadIdx.x] = 0u;
    else if (flat < 40)   VmeanRaw[(flat - 32) * 256 + threadIdx.x] = 0.f;
    else if (flat < 360)  uacc[(flat - 40) * 256 + threadIdx.x] = 0.f;   // 81920
    else if (flat < 365) { const int j = (flat - 360) * 256 + threadIdx.x;
                           if (j < NH * BATCH * NTOP) wsum[j] = 0.f; }

    const int xcd  = flat & 7;
    const int slot = flat >> 3;
    const int bh   = xcd * 4 + (slot >> 9);
    const int w    = threadIdx.x >> 6;
    const int lane = threadIdx.x & 63;
    const int l    = (slot & 511) * 4 + w;

    const int g  = lane >> 4;
    const int dl = lane & 15;

#if defined(__has_builtin) && __has_builtin(__builtin_nontemporal_load)
    const f32x4v q4 = __builtin_nontemporal_load(
        reinterpret_cast<const f32x4v*>(Qt + ((size_t)bh * LSEQ + l) * DHD + dl * 4));
#else
    const f32x4v q4 = *reinterpret_cast<const f32x4v*>(
        Qt + ((size_t)bh * LSEQ + l) * DHD + dl * 4);
#endif

    const float* Kb = Kt + (size_t)bh * LSEQ * DHD;
    float vmax = -FLT_MAX, vsum = 0.f;
#pragma unroll
    for (int it = 0; it < 10; ++it) {
        const int s = it * 4 + g;
        const int ks = idxs[l * NSAMP + s];
        const float4 k4 = *reinterpret_cast<const float4*>(
            Kb + (size_t)ks * DHD + dl * 4);
        float p = q4[0] * k4.x + q4[1] * k4.y + q4[2] * k4.z + q4[3] * k4.w;
        p += __shfl_xor(p, 1);
        p += __shfl_xor(p, 2);
        p += __shfl_xor(p, 4);
        p += __shfl_xor(p, 8);
        vmax = fmaxf(vmax, p);
        vsum += p;
    }
    vmax = fmaxf(vmax, __shfl_xor(vmax, 16));
    vsum += __shfl_xor(vsum, 16);
    vmax = fmaxf(vmax, __shfl_xor(vmax, 32));
    vsum += __shfl_xor(vsum, 32);
    if (lane == 0) M[(size_t)bh * LSEQ + l] = vmax - vsum * (1.0f / LSEQ);
}

// ---------------------------------------------------------------------------
// K3: stable top-40 per (b,h); candidates in registers.
// ---------------------------------------------------------------------------
__global__ __launch_bounds__(256) void topk_kernel(
    const float* __restrict__ M, int* __restrict__ topidx,
    unsigned* __restrict__ headmask, unsigned char* __restrict__ slot)
{
    const int bh = blockIdx.x;
    const int b = bh >> 3, h = bh & 7;
    const int w = threadIdx.x >> 6, lane = threadIdx.x & 63;
    const int base = threadIdx.x * 8;

    float e[8];
    {
        const float4 v0 = *reinterpret_cast<const float4*>(M + (size_t)bh * LSEQ + base);
        const float4 v1 = *reinterpret_cast<const float4*>(M + (size_t)bh * LSEQ + base + 4);
        e[0] = v0.x; e[1] = v0.y; e[2] = v0.z; e[3] = v0.w;
        e[4] = v1.x; e[5] = v1.y; e[6] = v1.z; e[7] = v1.w;
    }

    __shared__ float rv[4];
    __shared__ int   ri[4];
    __shared__ int   winner;

    for (int t = 0; t < NTOP; ++t) {
        float bv = e[0]; int br = 0;
#pragma unroll
        for (int r = 1; r < 8; ++r)
            if (e[r] > bv) { bv = e[r]; br = r; }
        int bi = base + br;
#pragma unroll
        for (int off = 32; off; off >>= 1) {
            const float ov = __shfl_xor(bv, off);
            const int   oi = __shfl_xor(bi, off);
            if (ov > bv || (ov == bv && oi < bi)) { bv = ov; bi = oi; }
        }
        if (lane == 0) { rv[w] = bv; ri[w] = bi; }
        __syncthreads();
        if (threadIdx.x == 0) {
            float fv = rv[0]; int fi = ri[0];
#pragma unroll
            for (int k = 1; k < 4; ++k)
                if (rv[k] > fv || (rv[k] == fv && ri[k] < fi)) { fv = rv[k]; fi = ri[k]; }
            topidx[bh * NTOP + t] = fi;
            atomicOr(&headmask[b * LSEQ + fi], 1u << h);
            slot[bh * LSEQ + fi] = (unsigned char)t;
            winner = fi;
        }
        __syncthreads();
        const int fi = winner;
        if ((fi >> 3) == threadIdx.x) e[fi & 7] = -FLT_MAX;
    }
}

// ---------------------------------------------------------------------------
// K4: flash split-K attention partials + V column-sum accumulation.
// v4: partial PV and exp-sums go DIRECTLY to global accumulators via
// atomicAdd (uacc, wsum) — kills the 21 MB pacc round-trip and the
// latency-bound combine reduction (was 60 us at 1.7% occupancy).
// ---------------------------------------------------------------------------
__global__ __launch_bounds__(256) void attn_partial(
    const float* __restrict__ Qt, const float* __restrict__ Kt,
    const float* __restrict__ Vt, const int* __restrict__ topidx,
    float* __restrict__ wsum, float* __restrict__ uacc,
    float* __restrict__ VmeanRaw)
{
    const int bh = blockIdx.x;
    const int c  = blockIdx.y;
    const int kbase = c * TK;
    const int tid = threadIdx.x;

    __shared__ float Qs[NTOP][DHD];      // 10240 B
    __shared__ float Ks[TK][68];         //  8704 B
    __shared__ float Vs[TK][68];         //  8704 B
    __shared__ float Sc[TK][52];         //  6656 B  -> total 34304 B

    for (int i = tid; i < NTOP * DHD; i += 256) {
        const int q = i >> 6, d = i & 63;
        const int row = topidx[bh * NTOP + q];
        Qs[q][d] = Qt[((size_t)bh * LSEQ + row) * DHD + d];
    }
    {
        const int r0 = tid >> 4, c4 = tid & 15;
#pragma unroll
        for (int rr = 0; rr < 2; ++rr) {
            const int r = r0 + rr * 16;
            const size_t g = ((size_t)bh * LSEQ + kbase + r) * DHD + c4 * 4;
            *reinterpret_cast<float4*>(&Ks[r][c4 * 4]) =
                *reinterpret_cast<const float4*>(Kt + g);
            *reinterpret_cast<float4*>(&Vs[r][c4 * 4]) =
                *reinterpret_cast<const float4*>(Vt + g);
        }
    }
    __syncthreads();

    // V column partial sums (vmean fold-in)
    {
        const int d = tid & 63, part = tid >> 6;
        float s = 0.f;
#pragma unroll
        for (int i = 0; i < 8; ++i) s += Vs[part * 8 + i][d];
        atomicAdd(&VmeanRaw[bh * DHD + d], s);
    }

    // scores: thread -> (kloc = tid&15, qg = tid>>4); k = kloc + kb*16, kb<2
    {
        const int kloc = tid & 15, qg = tid >> 4;
#pragma unroll
        for (int qit = 0; qit < 3; ++qit) {
            const int q = qg + qit * 16;
            if (q < NTOP) {
#pragma unroll
                for (int kb = 0; kb < 2; ++kb) {
                    const int k = kloc + kb * 16;
                    float acc = 0.f;
#pragma unroll
                    for (int j = 0; j < 16; ++j) {
                        const float4 kv = *reinterpret_cast<const float4*>(&Ks[k][j * 4]);
                        const float4 qv = *reinterpret_cast<const float4*>(&Qs[q][j * 4]);
                        acc += qv.x * kv.x + qv.y * kv.y + qv.z * kv.z + qv.w * kv.w;
                    }
                    Sc[k][q] = acc * QK_SCALE;
                }
            }
        }
    }
    __syncthreads();

    // exp + per-chunk sums -> global atomic
    {
        const int w = tid >> 6, lane = tid & 63;
        const int k = lane & 31;
#pragma unroll
        for (int j = 0; j < 10; ++j) {
            const int q = w * 10 + j;
            const float ee = __expf(Sc[k][q]);
            float s = ee;
            s += __shfl_xor(s, 1);
            s += __shfl_xor(s, 2);
            s += __shfl_xor(s, 4);
            s += __shfl_xor(s, 8);
            s += __shfl_xor(s, 16);
            if (lane < 32) Sc[k][q] = ee;
            if (lane == 0) atomicAdd(&wsum[bh * NTOP + q], s);
        }
    }
    __syncthreads();

    // partial PV -> global atomic accumulate
    {
        const int d = tid & 63, g = tid >> 6;
        const int q0 = g * 12;
        const int nq = (g < 3) ? 12 : 4;
        float acc[12] = {};
        for (int k = 0; k < TK; ++k) {
            const float v = Vs[k][d];
            const float4 s0 = *reinterpret_cast<const float4*>(&Sc[k][q0]);
            acc[0] = fmaf(s0.x, v, acc[0]); acc[1] = fmaf(s0.y, v, acc[1]);
            acc[2] = fmaf(s0.z, v, acc[2]); acc[3] = fmaf(s0.w, v, acc[3]);
            if (g < 3) {
                const float4 s1 = *reinterpret_cast<const float4*>(&Sc[k][q0 + 4]);
                const float4 s2 = *reinterpret_cast<const float4*>(&Sc[k][q0 + 8]);
                acc[4] = fmaf(s1.x, v, acc[4]); acc[5]  = fmaf(s1.y, v, acc[5]);
                acc[6] = fmaf(s1.z, v, acc[6]); acc[7]  = fmaf(s1.w, v, acc[7]);
                acc[8] = fmaf(s2.x, v, acc[8]); acc[9]  = fmaf(s2.y, v, acc[9]);
                acc[10] = fmaf(s2.z, v, acc[10]); acc[11] = fmaf(s2.w, v, acc[11]);
            }
        }
#pragma unroll
        for (int j = 0; j < 12; ++j)
            if (j < nq)
                atomicAdd(&uacc[((size_t)bh * NTOP + q0 + j) * DHD + d], acc[j]);
    }
}

// ---------------------------------------------------------------------------
// K5: finalize — delta = uacc/wsum - vmean (flat elementwise; delta layout
// IS the flat index), plus 4 blocks computing meanout.
// ---------------------------------------------------------------------------
__global__ __launch_bounds__(256) void finalize_kernel(
    const float* __restrict__ wsum, const float* __restrict__ uacc,
    const float* __restrict__ VmeanRaw, const float* __restrict__ Wo,
    const float* __restrict__ bo, float* __restrict__ delta,
    float* __restrict__ meanout)
{
    const int blk = blockIdx.x;
    if (blk < 320) {                         // 320*256 = 81920 = 32*40*64
        const int idx = blk * 256 + threadIdx.x;
        const int bh = idx >> 11;            // /2560 ... careful: 2560 not pow2
        const int rem = idx - bh * 2560;
        // NOTE: idx>>11 != idx/2560; do exact division:
        const int bh2 = idx / 2560;
        const int rem2 = idx - bh2 * 2560;
        const int q = rem2 >> 6, d = rem2 & 63;
        (void)bh; (void)rem;
        const float vm = VmeanRaw[bh2 * DHD + d] * (1.0f / (float)LSEQ);
        delta[idx] = uacc[idx] / wsum[bh2 * NTOP + q] - vm;
    } else {                                 // blocks 320..323: meanout[b]
        const int b = blk - 320;
        __shared__ float mc[DMODEL];
        for (int i = threadIdx.x; i < DMODEL; i += 256)
            mc[i] = VmeanRaw[b * DMODEL + i] * (1.0f / (float)LSEQ);
        __syncthreads();
        for (int n = threadIdx.x; n < DMODEL; n += 256) {
            float acc = bo[n];
            const float* wr = Wo + (size_t)n * DMODEL;
            for (int k = 0; k < DMODEL; ++k) acc = fmaf(mc[k], wr[k], acc);
            meanout[b * DMODEL + n] = acc;
        }
    }
}

// ---------------------------------------------------------------------------
// K6a: broadcast mean rows to ALL output rows (pure streaming write).
// ---------------------------------------------------------------------------
__global__ __launch_bounds__(256) void out_base(
    const float* __restrict__ meanout, float* __restrict__ out)
{
    const int total4 = BATCH * LSEQ * (DMODEL / 4);   // 2^20
    for (int i = blockIdx.x * 256 + threadIdx.x; i < total4; i += gridDim.x * 256) {
        const int row = i >> 7;
        const int b = row >> 11;
        const int c = i & 127;
        reinterpret_cast<float4*>(out)[i] =
            reinterpret_cast<const float4*>(meanout)[b * 128 + c];
    }
}

// ---------------------------------------------------------------------------
// K6b: scatter-add selected rows: out[b,l,:] += delta[bh,u] @ Wo_h^T.
// ---------------------------------------------------------------------------
__global__ __launch_bounds__(128) void out_scatter(
    const int* __restrict__ topidx, const float* __restrict__ delta,
    const float* __restrict__ Wo, float* __restrict__ out)
{
    const int bh = blockIdx.x;
    const int u  = blockIdx.y;
    const int b = bh >> 3, h = bh & 7;
    const int l = topidx[bh * NTOP + u];

    __shared__ float dl[DHD];
    if (threadIdx.x < DHD)
        dl[threadIdx.x] = delta[((size_t)bh * NTOP + u) * DHD + threadIdx.x];
    __syncthreads();

    float* orow = out + ((size_t)b * LSEQ + l) * DMODEL;
#pragma unroll
    for (int c = 0; c < 4; ++c) {
        const int n = threadIdx.x * 4 + c;
        const float4* wr4 = reinterpret_cast<const float4*>(
            Wo + (size_t)n * DMODEL + h * DHD);
        float a = 0.f;
#pragma unroll
        for (int dd = 0; dd < 16; ++dd) {
            const float4 wv = wr4[dd];
            a += dl[dd * 4 + 0] * wv.x + dl[dd * 4 + 1] * wv.y +
                 dl[dd * 4 + 2] * wv.z + dl[dd * 4 + 3] * wv.w;
        }
        atomicAdd(&orow[n], a);
    }
}

// ---------------------------------------------------------------------------
extern "C" void kernel_launch(void* const* d_in, const int* in_sizes, int n_in,
                              void* d_out, int out_size, void* d_ws, size_t ws_size,
                              hipStream_t stream)
{
    (void)in_sizes; (void)n_in; (void)out_size; (void)ws_size;
    const float* x     = (const float*)d_in[0];
    const float* ctxin = (const float*)d_in[1];
    const float* Wq    = (const float*)d_in[2];
    const float* bq    = (const float*)d_in[3];
    const float* Wk    = (const float*)d_in[4];
    const float* bk    = (const float*)d_in[5];
    const float* Wv    = (const float*)d_in[6];
    const float* bv    = (const float*)d_in[7];
    const float* Wo    = (const float*)d_in[8];
    const float* bo    = (const float*)d_in[9];
    const int*   idxs  = (const int*)d_in[10];
    float* out = (float*)d_out;

    char* ws = (char*)d_ws;
    size_t off = 0;
    auto alloc = [&](size_t bytes) -> void* {
        void* p = ws + off;
        off += (bytes + 255) & ~(size_t)255;
        return p;
    };

    const size_t qkv_bytes = (size_t)BATCH * NH * LSEQ * DHD * sizeof(float);
    float*         Qt       = (float*)alloc(qkv_bytes);
    float*         Kt       = (float*)alloc(qkv_bytes);
    float*         Vt       = (float*)alloc(qkv_bytes);
    float*         Mbuf     = (float*)alloc((size_t)BATCH * NH * LSEQ * sizeof(float));
    float*         VmeanRaw = (float*)alloc((size_t)BATCH * NH * DHD * sizeof(float));
    float*         meanout  = (float*)alloc((size_t)BATCH * DMODEL * sizeof(float));
    float*         delta    = (float*)alloc((size_t)BATCH * NH * NTOP * DHD * sizeof(float));
    int*           topidx   = (int*)alloc((size_t)BATCH * NH * NTOP * sizeof(int));
    unsigned*      headmask = (unsigned*)alloc((size_t)BATCH * LSEQ * sizeof(unsigned));
    unsigned char* slot     = (unsigned char*)alloc((size_t)BATCH * NH * LSEQ);
    float*         wsum     = (float*)alloc((size_t)BATCH * NH * NTOP * sizeof(float));
    float*         uacc     = (float*)alloc((size_t)BATCH * NH * NTOP * DHD * sizeof(float));
    u16*           xsP      = (u16*)alloc(ASTRIDE * 3 * 2);
    u16*           csP      = (u16*)alloc(ASTRIDE * 3 * 2);
    u16*           wqP      = (u16*)alloc(WSTRIDE * 3 * 2);
    u16*           wkP      = (u16*)alloc(WSTRIDE * 3 * 2);
    u16*           wvP      = (u16*)alloc(WSTRIDE * 3 * 2);

    split3_all<<<2048, 256, 0, stream>>>(x, ctxin, Wq, Wk, Wv,
                                         xsP, csP, wqP, wkP, wvP);

    gemm_mfma<3><<<dim3(256, 2), 256, 0, stream>>>(
        xsP, wqP, csP, wkP, bq, bk, Qt, Kt);

    gemm_mfma<2><<<dim3(256, 1), 256, 0, stream>>>(
        csP, wvP, csP, wvP, bv, bv, Vt, Vt);

    score_kernel<<<(BATCH * NH * LSEQ) / 4, 256, 0, stream>>>(
        Qt, Kt, idxs, Mbuf, headmask, VmeanRaw, uacc, wsum);

    topk_kernel<<<BATCH * NH, 256, 0, stream>>>(Mbuf, topidx, headmask, slot);

    attn_partial<<<dim3(BATCH * NH, NCHUNK), 256, 0, stream>>>(
        Qt, Kt, Vt, topidx, wsum, uacc, VmeanRaw);

    finalize_kernel<<<324, 256, 0, stream>>>(
        wsum, uacc, VmeanRaw, Wo, bo, delta, meanout);

    out_base<<<2048, 256, 0, stream>>>(meanout, out);

    out_scatter<<<dim3(BATCH * NH, NTOP), 128, 0, stream>>>(
        topidx, delta, Wo, out);
}

// Round 14
// 280.613 us; speedup vs baseline: 1.1786x; 1.0489x over previous
//
#include <hip/hip_runtime.h>
#include <float.h>

#define BATCH 4
#define LSEQ  2048
#define DMODEL 512
#define NH    8
#define DHD   64
#define NSAMP 40
#define NTOP  40
#define TK    32
#define CPB   4                  // chunks per block in attn_partial
#define NSEG  16                 // 16 segs * 4 chunks * 32 keys = 2048
#define QK_SCALE 0.125f

typedef unsigned short u16;
typedef __attribute__((ext_vector_type(8))) short short8b;  // 8 bf16 = 16 B
typedef __attribute__((ext_vector_type(4))) float f32x4;
typedef __attribute__((ext_vector_type(4))) float f32x4v;

#define ASTRIDE ((size_t)BATCH * LSEQ * DMODEL)   // 4,194,304 elems (2^22)
#define WSTRIDE ((size_t)DMODEL * DMODEL)         //   262,144 elems (2^18)

// RTNE float->bf16 on raw bits (inputs finite).
static __device__ __forceinline__ u16 f2bf(float x) {
    unsigned u = __float_as_uint(x);
    u += 0x7FFFu + ((u >> 16) & 1u);
    return (u16)(u >> 16);
}
static __device__ __forceinline__ float bf2f(u16 s) {
    return __uint_as_float((unsigned)s << 16);
}

// ---------------------------------------------------------------------------
// K0: unified 3-way bf16 split, ONE dispatch. x = p1+p2+p3 + O(2^-27|x|).
// ---------------------------------------------------------------------------
__global__ __launch_bounds__(256) void split3_all(
    const float* __restrict__ x, const float* __restrict__ ctxin,
    const float* __restrict__ Wq, const float* __restrict__ Wk,
    const float* __restrict__ Wv,
    u16* __restrict__ xsP, u16* __restrict__ csP,
    u16* __restrict__ wqP, u16* __restrict__ wkP, u16* __restrict__ wvP)
{
    const int X4 = 1 << 20;
    const int W4 = 1 << 16;
    const int total = 2 * X4 + 3 * W4;
    for (int i = blockIdx.x * 256 + threadIdx.x; i < total; i += gridDim.x * 256) {
        const float* src; u16* dst; size_t pstride; int i4;
        if (i < X4)            { src = x;     dst = xsP; pstride = ASTRIDE; i4 = i; }
        else if (i < 2 * X4)   { src = ctxin; dst = csP; pstride = ASTRIDE; i4 = i - X4; }
        else {
            const int w = i - 2 * X4;
            const int which = w >> 16, rem = w & (W4 - 1);
            src = (which == 0) ? Wq : (which == 1) ? Wk : Wv;
            dst = (which == 0) ? wqP : (which == 1) ? wkP : wvP;
            pstride = WSTRIDE; i4 = rem;
        }
        const float4 v = reinterpret_cast<const float4*>(src)[i4];
        const float in[4] = {v.x, v.y, v.z, v.w};
        ushort4 o1, o2, o3;
        u16 b1[4], b2[4], b3[4];
#pragma unroll
        for (int c = 0; c < 4; ++c) {
            const float xx = in[c];
            b1[c] = f2bf(xx);
            const float r1 = xx - bf2f(b1[c]);
            b2[c] = f2bf(r1);
            b3[c] = f2bf(r1 - bf2f(b2[c]));
        }
        o1.x = b1[0]; o1.y = b1[1]; o1.z = b1[2]; o1.w = b1[3];
        o2.x = b2[0]; o2.y = b2[1]; o2.z = b2[2]; o2.w = b2[3];
        o3.x = b3[0]; o3.y = b3[1]; o3.z = b3[2]; o3.w = b3[3];
        reinterpret_cast<ushort4*>(dst)[i4]                = o1;
        reinterpret_cast<ushort4*>(dst + pstride)[i4]      = o2;
        reinterpret_cast<ushort4*>(dst + 2 * pstride)[i4]  = o3;
    }
}

// ---------------------------------------------------------------------------
// K1: GEMM on MFMA, bf16xNP planes. NP=3 (Q,K): fp32-accuracy 6-product.
// NP=2 (V): 3-product, err ~1e-5 (V never feeds top-k). Tile 128x128.
// ---------------------------------------------------------------------------
template<int NP>
__global__ __launch_bounds__(256) void gemm_mfma(
    const u16* __restrict__ A0, const u16* __restrict__ W0,
    const u16* __restrict__ A1, const u16* __restrict__ W1,
    const float* __restrict__ bias0, const float* __restrict__ bias1,
    float* __restrict__ Out0, float* __restrict__ Out1)
{
    const int z = blockIdx.y;
    const int i = blockIdx.x;
    const int xcd = i & 7;
    const int loc = i >> 3;
    const int m0 = (xcd * 8 + (loc & 7)) * 128;
    const int n0 = (loc >> 3) * 128;

    const u16* __restrict__ Ap   = z ? A1 : A0;
    const u16* __restrict__ Wp   = z ? W1 : W0;
    const float* __restrict__ bias = z ? bias1 : bias0;
    float*       __restrict__ Out  = z ? Out1 : Out0;

    __shared__ u16 As[NP][128][40];
    __shared__ u16 Ws[NP][128][40];

    const int tid  = threadIdx.x;
    const int w    = tid >> 6;
    const int lane = tid & 63;
    const int wm   = w >> 1;
    const int wn   = w & 1;
    const int lr   = lane & 15;
    const int lg   = lane >> 4;

    const int srow = tid >> 1;
    const int sc   = (tid & 1) * 16;

    f32x4 acc[4][4];
#pragma unroll
    for (int mf = 0; mf < 4; ++mf)
#pragma unroll
        for (int nf = 0; nf < 4; ++nf)
#pragma unroll
            for (int r = 0; r < 4; ++r) acc[mf][nf][r] = 0.f;

    short8b sa[NP][2], sw[NP][2];
#pragma unroll
    for (int p = 0; p < NP; ++p) {
        const u16* asrc = Ap + p * ASTRIDE + (size_t)(m0 + srow) * DMODEL + sc;
        const u16* wsrc = Wp + p * WSTRIDE + (size_t)(n0 + srow) * DMODEL + sc;
        sa[p][0] = *reinterpret_cast<const short8b*>(asrc);
        sa[p][1] = *reinterpret_cast<const short8b*>(asrc + 8);
        sw[p][0] = *reinterpret_cast<const short8b*>(wsrc);
        sw[p][1] = *reinterpret_cast<const short8b*>(wsrc + 8);
    }

    for (int k0 = 0; k0 < DMODEL; k0 += 32) {
#pragma unroll
        for (int p = 0; p < NP; ++p) {
            *reinterpret_cast<short8b*>(&As[p][srow][sc])     = sa[p][0];
            *reinterpret_cast<short8b*>(&As[p][srow][sc + 8]) = sa[p][1];
            *reinterpret_cast<short8b*>(&Ws[p][srow][sc])     = sw[p][0];
            *reinterpret_cast<short8b*>(&Ws[p][srow][sc + 8]) = sw[p][1];
        }
        __syncthreads();

        if (k0 + 32 < DMODEL) {
#pragma unroll
            for (int p = 0; p < NP; ++p) {
                const u16* asrc =
                    Ap + p * ASTRIDE + (size_t)(m0 + srow) * DMODEL + k0 + 32 + sc;
                const u16* wsrc =
                    Wp + p * WSTRIDE + (size_t)(n0 + srow) * DMODEL + k0 + 32 + sc;
                sa[p][0] = *reinterpret_cast<const short8b*>(asrc);
                sa[p][1] = *reinterpret_cast<const short8b*>(asrc + 8);
                sw[p][0] = *reinterpret_cast<const short8b*>(wsrc);
                sw[p][1] = *reinterpret_cast<const short8b*>(wsrc + 8);
            }
        }

        short8b af[4][NP];
#pragma unroll
        for (int mf = 0; mf < 4; ++mf) {
            const int row = wm * 64 + mf * 16 + lr;
#pragma unroll
            for (int p = 0; p < NP; ++p)
                af[mf][p] = *reinterpret_cast<const short8b*>(&As[p][row][lg * 8]);
        }
#pragma unroll
        for (int nf = 0; nf < 4; ++nf) {
            const int row = wn * 64 + nf * 16 + lr;
            const short8b b1 = *reinterpret_cast<const short8b*>(&Ws[0][row][lg * 8]);
            const short8b b2 = *reinterpret_cast<const short8b*>(&Ws[1][row][lg * 8]);
#pragma unroll
            for (int mf = 0; mf < 4; ++mf) {
                acc[mf][nf] = __builtin_amdgcn_mfma_f32_16x16x32_bf16(af[mf][0], b1, acc[mf][nf], 0, 0, 0);
                acc[mf][nf] = __builtin_amdgcn_mfma_f32_16x16x32_bf16(af[mf][1], b1, acc[mf][nf], 0, 0, 0);
                acc[mf][nf] = __builtin_amdgcn_mfma_f32_16x16x32_bf16(af[mf][0], b2, acc[mf][nf], 0, 0, 0);
                if constexpr (NP == 3) {
                    const short8b b3 = *reinterpret_cast<const short8b*>(&Ws[2][row][lg * 8]);
                    acc[mf][nf] = __builtin_amdgcn_mfma_f32_16x16x32_bf16(af[mf][2], b1, acc[mf][nf], 0, 0, 0);
                    acc[mf][nf] = __builtin_amdgcn_mfma_f32_16x16x32_bf16(af[mf][0], b3, acc[mf][nf], 0, 0, 0);
                    acc[mf][nf] = __builtin_amdgcn_mfma_f32_16x16x32_bf16(af[mf][1], b2, acc[mf][nf], 0, 0, 0);
                }
            }
        }
        __syncthreads();
    }

#pragma unroll
    for (int nf = 0; nf < 4; ++nf) {
        const int n = n0 + wn * 64 + nf * 16 + lr;
        const int h = n >> 6, d = n & 63;
        const float bv_ = bias[n];
#pragma unroll
        for (int mf = 0; mf < 4; ++mf) {
#pragma unroll
            for (int r = 0; r < 4; ++r) {
                const int m = m0 + wm * 64 + mf * 16 + lg * 4 + r;
                const int b = m >> 11, l = m & (LSEQ - 1);
                Out[((size_t)(b * NH + h) * LSEQ + l) * DHD + d] = acc[mf][nf][r] + bv_;
            }
        }
    }
}

// ---------------------------------------------------------------------------
// K2: sampled sparsity measure + zero-init of headmask/VmeanRaw/uacc/wsum.
// Runs IMMEDIATELY after gemm<3>: Kt (2 MB/XCD) still L2-warm from the
// GEMM's writes — gather hits L2 instead of L3.
// ---------------------------------------------------------------------------
__global__ __launch_bounds__(256) void score_kernel(
    const float* __restrict__ Qt, const float* __restrict__ Kt,
    const int* __restrict__ idxs, float* __restrict__ M,
    unsigned* __restrict__ headmask, float* __restrict__ VmeanRaw,
    float* __restrict__ uacc, float* __restrict__ wsum)
{
    const int flat = blockIdx.x;
    if (flat < 32)        headmask[flat * 256 + threadIdx.x] = 0u;
    else if (flat < 40)   VmeanRaw[(flat - 32) * 256 + threadIdx.x] = 0.f;
    else if (flat < 360)  uacc[(flat - 40) * 256 + threadIdx.x] = 0.f;   // 81920
    else if (flat < 365) { const int j = (flat - 360) * 256 + threadIdx.x;
                           if (j < NH * BATCH * NTOP) wsum[j] = 0.f; }

    const int xcd  = flat & 7;
    const int slot = flat >> 3;
    const int bh   = xcd * 4 + (slot >> 9);
    const int w    = threadIdx.x >> 6;
    const int lane = threadIdx.x & 63;
    const int l    = (slot & 511) * 4 + w;

    const int g  = lane >> 4;
    const int dl = lane & 15;

#if defined(__has_builtin) && __has_builtin(__builtin_nontemporal_load)
    const f32x4v q4 = __builtin_nontemporal_load(
        reinterpret_cast<const f32x4v*>(Qt + ((size_t)bh * LSEQ + l) * DHD + dl * 4));
#else
    const f32x4v q4 = *reinterpret_cast<const f32x4v*>(
        Qt + ((size_t)bh * LSEQ + l) * DHD + dl * 4);
#endif

    const float* Kb = Kt + (size_t)bh * LSEQ * DHD;
    float vmax = -FLT_MAX, vsum = 0.f;
#pragma unroll
    for (int it = 0; it < 10; ++it) {
        const int s = it * 4 + g;
        const int ks = idxs[l * NSAMP + s];
        const float4 k4 = *reinterpret_cast<const float4*>(
            Kb + (size_t)ks * DHD + dl * 4);
        float p = q4[0] * k4.x + q4[1] * k4.y + q4[2] * k4.z + q4[3] * k4.w;
        p += __shfl_xor(p, 1);
        p += __shfl_xor(p, 2);
        p += __shfl_xor(p, 4);
        p += __shfl_xor(p, 8);
        vmax = fmaxf(vmax, p);
        vsum += p;
    }
    vmax = fmaxf(vmax, __shfl_xor(vmax, 16));
    vsum += __shfl_xor(vsum, 16);
    vmax = fmaxf(vmax, __shfl_xor(vmax, 32));
    vsum += __shfl_xor(vsum, 32);
    if (lane == 0) M[(size_t)bh * LSEQ + l] = vmax - vsum * (1.0f / LSEQ);
}

// ---------------------------------------------------------------------------
// K3: stable top-40 per (b,h); candidates in registers.
// ---------------------------------------------------------------------------
__global__ __launch_bounds__(256) void topk_kernel(
    const float* __restrict__ M, int* __restrict__ topidx,
    unsigned* __restrict__ headmask, unsigned char* __restrict__ slot)
{
    const int bh = blockIdx.x;
    const int b = bh >> 3, h = bh & 7;
    const int w = threadIdx.x >> 6, lane = threadIdx.x & 63;
    const int base = threadIdx.x * 8;

    float e[8];
    {
        const float4 v0 = *reinterpret_cast<const float4*>(M + (size_t)bh * LSEQ + base);
        const float4 v1 = *reinterpret_cast<const float4*>(M + (size_t)bh * LSEQ + base + 4);
        e[0] = v0.x; e[1] = v0.y; e[2] = v0.z; e[3] = v0.w;
        e[4] = v1.x; e[5] = v1.y; e[6] = v1.z; e[7] = v1.w;
    }

    __shared__ float rv[4];
    __shared__ int   ri[4];
    __shared__ int   winner;

    for (int t = 0; t < NTOP; ++t) {
        float bv = e[0]; int br = 0;
#pragma unroll
        for (int r = 1; r < 8; ++r)
            if (e[r] > bv) { bv = e[r]; br = r; }
        int bi = base + br;
#pragma unroll
        for (int off = 32; off; off >>= 1) {
            const float ov = __shfl_xor(bv, off);
            const int   oi = __shfl_xor(bi, off);
            if (ov > bv || (ov == bv && oi < bi)) { bv = ov; bi = oi; }
        }
        if (lane == 0) { rv[w] = bv; ri[w] = bi; }
        __syncthreads();
        if (threadIdx.x == 0) {
            float fv = rv[0]; int fi = ri[0];
#pragma unroll
            for (int k = 1; k < 4; ++k)
                if (rv[k] > fv || (rv[k] == fv && ri[k] < fi)) { fv = rv[k]; fi = ri[k]; }
            topidx[bh * NTOP + t] = fi;
            atomicOr(&headmask[b * LSEQ + fi], 1u << h);
            slot[bh * LSEQ + fi] = (unsigned char)t;
            winner = fi;
        }
        __syncthreads();
        const int fi = winner;
        if ((fi >> 3) == threadIdx.x) e[fi & 7] = -FLT_MAX;
    }
}

// ---------------------------------------------------------------------------
// K4: flash split-K attention partials + V column-sum accumulation.
// v5: grid (32 bh, 16 segs); each block loops over CPB=4 chunks of TK=32.
// Q staged ONCE per block (gather 20->5 MB); PV/wsum/vsum accumulate in
// REGISTERS across chunks (exp values absolute - no rescale needed);
// atomics issued once at the end (5.24M -> 1.31M).
// ---------------------------------------------------------------------------
__global__ __launch_bounds__(256) void attn_partial(
    const float* __restrict__ Qt, const float* __restrict__ Kt,
    const float* __restrict__ Vt, const int* __restrict__ topidx,
    float* __restrict__ wsum, float* __restrict__ uacc,
    float* __restrict__ VmeanRaw)
{
    const int bh  = blockIdx.x;
    const int seg = blockIdx.y;
    const int tid = threadIdx.x;

    __shared__ float Qs[NTOP][DHD];      // 10240 B
    __shared__ float Ks[TK][68];         //  8704 B
    __shared__ float Vs[TK][68];         //  8704 B
    __shared__ float Sc[TK][52];         //  6656 B  -> total 34304 B

    for (int i = tid; i < NTOP * DHD; i += 256) {
        const int q = i >> 6, d = i & 63;
        const int row = topidx[bh * NTOP + q];
        Qs[q][d] = Qt[((size_t)bh * LSEQ + row) * DHD + d];
    }

    // cross-chunk register accumulators
    const int dpv = tid & 63, gpv = tid >> 6;
    const int q0 = gpv * 12;
    const int nq = (gpv < 3) ? 12 : 4;
    float pv[12] = {};
    float ws[10] = {};
    float vsacc = 0.f;
    const int wv = tid >> 6, lane = tid & 63;
    const int kred = lane & 31;

    for (int cc = 0; cc < CPB; ++cc) {
        const int kbase = (seg * CPB + cc) * TK;
        __syncthreads();                  // Qs ready (cc=0) / PV done (cc>0)

        {
            const int r0 = tid >> 4, c4 = tid & 15;
#pragma unroll
            for (int rr = 0; rr < 2; ++rr) {
                const int r = r0 + rr * 16;
                const size_t g = ((size_t)bh * LSEQ + kbase + r) * DHD + c4 * 4;
                *reinterpret_cast<float4*>(&Ks[r][c4 * 4]) =
                    *reinterpret_cast<const float4*>(Kt + g);
                *reinterpret_cast<float4*>(&Vs[r][c4 * 4]) =
                    *reinterpret_cast<const float4*>(Vt + g);
            }
        }
        __syncthreads();

        // V column partial sums -> register
        {
#pragma unroll
            for (int i = 0; i < 8; ++i) vsacc += Vs[gpv * 8 + i][dpv];
        }

        // scores: thread -> (kloc = tid&15, qg = tid>>4)
        {
            const int kloc = tid & 15, qg = tid >> 4;
#pragma unroll
            for (int qit = 0; qit < 3; ++qit) {
                const int q = qg + qit * 16;
                if (q < NTOP) {
#pragma unroll
                    for (int kb = 0; kb < 2; ++kb) {
                        const int k = kloc + kb * 16;
                        float acc = 0.f;
#pragma unroll
                        for (int j = 0; j < 16; ++j) {
                            const float4 kv = *reinterpret_cast<const float4*>(&Ks[k][j * 4]);
                            const float4 qv = *reinterpret_cast<const float4*>(&Qs[q][j * 4]);
                            acc += qv.x * kv.x + qv.y * kv.y + qv.z * kv.z + qv.w * kv.w;
                        }
                        Sc[k][q] = acc * QK_SCALE;
                    }
                }
            }
        }
        __syncthreads();

        // exp + per-chunk sums -> register accumulate
        {
#pragma unroll
            for (int j = 0; j < 10; ++j) {
                const int q = wv * 10 + j;
                const float ee = __expf(Sc[kred][q]);
                float s = ee;
                s += __shfl_xor(s, 1);
                s += __shfl_xor(s, 2);
                s += __shfl_xor(s, 4);
                s += __shfl_xor(s, 8);
                s += __shfl_xor(s, 16);
                if (lane < 32) Sc[kred][q] = ee;
                ws[j] += s;                       // only lane 0's copy used
            }
        }
        __syncthreads();

        // partial PV -> register accumulate
        {
            for (int k = 0; k < TK; ++k) {
                const float v = Vs[k][dpv];
                const float4 s0 = *reinterpret_cast<const float4*>(&Sc[k][q0]);
                pv[0] = fmaf(s0.x, v, pv[0]); pv[1] = fmaf(s0.y, v, pv[1]);
                pv[2] = fmaf(s0.z, v, pv[2]); pv[3] = fmaf(s0.w, v, pv[3]);
                if (gpv < 3) {
                    const float4 s1 = *reinterpret_cast<const float4*>(&Sc[k][q0 + 4]);
                    const float4 s2 = *reinterpret_cast<const float4*>(&Sc[k][q0 + 8]);
                    pv[4] = fmaf(s1.x, v, pv[4]); pv[5]  = fmaf(s1.y, v, pv[5]);
                    pv[6] = fmaf(s1.z, v, pv[6]); pv[7]  = fmaf(s1.w, v, pv[7]);
                    pv[8] = fmaf(s2.x, v, pv[8]); pv[9]  = fmaf(s2.y, v, pv[9]);
                    pv[10] = fmaf(s2.z, v, pv[10]); pv[11] = fmaf(s2.w, v, pv[11]);
                }
            }
        }
    }

    // single atomic flush per block
    atomicAdd(&VmeanRaw[bh * DHD + dpv], vsacc);
    if (lane == 0) {
#pragma unroll
        for (int j = 0; j < 10; ++j)
            atomicAdd(&wsum[bh * NTOP + wv * 10 + j], ws[j]);
    }
#pragma unroll
    for (int j = 0; j < 12; ++j)
        if (j < nq)
            atomicAdd(&uacc[((size_t)bh * NTOP + q0 + j) * DHD + dpv], pv[j]);
}

// ---------------------------------------------------------------------------
// K5: finalize — delta = uacc/wsum - vmean (flat), + 4 meanout blocks.
// ---------------------------------------------------------------------------
__global__ __launch_bounds__(256) void finalize_kernel(
    const float* __restrict__ wsum, const float* __restrict__ uacc,
    const float* __restrict__ VmeanRaw, const float* __restrict__ Wo,
    const float* __restrict__ bo, float* __restrict__ delta,
    float* __restrict__ meanout)
{
    const int blk = blockIdx.x;
    if (blk < 320) {                         // 320*256 = 81920 = 32*40*64
        const int idx = blk * 256 + threadIdx.x;
        const int bh = idx / 2560;
        const int rem = idx - bh * 2560;
        const int q = rem >> 6, d = rem & 63;
        const float vm = VmeanRaw[bh * DHD + d] * (1.0f / (float)LSEQ);
        delta[idx] = uacc[idx] / wsum[bh * NTOP + q] - vm;
    } else {                                 // blocks 320..323: meanout[b]
        const int b = blk - 320;
        __shared__ float mc[DMODEL];
        for (int i = threadIdx.x; i < DMODEL; i += 256)
            mc[i] = VmeanRaw[b * DMODEL + i] * (1.0f / (float)LSEQ);
        __syncthreads();
        for (int n = threadIdx.x; n < DMODEL; n += 256) {
            float acc = bo[n];
            const float* wr = Wo + (size_t)n * DMODEL;
            for (int k = 0; k < DMODEL; ++k) acc = fmaf(mc[k], wr[k], acc);
            meanout[b * DMODEL + n] = acc;
        }
    }
}

// ---------------------------------------------------------------------------
// K6a: broadcast mean rows to ALL output rows (pure streaming write).
// ---------------------------------------------------------------------------
__global__ __launch_bounds__(256) void out_base(
    const float* __restrict__ meanout, float* __restrict__ out)
{
    const int total4 = BATCH * LSEQ * (DMODEL / 4);   // 2^20
    for (int i = blockIdx.x * 256 + threadIdx.x; i < total4; i += gridDim.x * 256) {
        const int row = i >> 7;
        const int b = row >> 11;
        const int c = i & 127;
        reinterpret_cast<float4*>(out)[i] =
            reinterpret_cast<const float4*>(meanout)[b * 128 + c];
    }
}

// ---------------------------------------------------------------------------
// K6b: scatter-add selected rows: out[b,l,:] += delta[bh,u] @ Wo_h^T.
// ---------------------------------------------------------------------------
__global__ __launch_bounds__(128) void out_scatter(
    const int* __restrict__ topidx, const float* __restrict__ delta,
    const float* __restrict__ Wo, float* __restrict__ out)
{
    const int bh = blockIdx.x;
    const int u  = blockIdx.y;
    const int b = bh >> 3, h = bh & 7;
    const int l = topidx[bh * NTOP + u];

    __shared__ float dl[DHD];
    if (threadIdx.x < DHD)
        dl[threadIdx.x] = delta[((size_t)bh * NTOP + u) * DHD + threadIdx.x];
    __syncthreads();

    float* orow = out + ((size_t)b * LSEQ + l) * DMODEL;
#pragma unroll
    for (int c = 0; c < 4; ++c) {
        const int n = threadIdx.x * 4 + c;
        const float4* wr4 = reinterpret_cast<const float4*>(
            Wo + (size_t)n * DMODEL + h * DHD);
        float a = 0.f;
#pragma unroll
        for (int dd = 0; dd < 16; ++dd) {
            const float4 wv = wr4[dd];
            a += dl[dd * 4 + 0] * wv.x + dl[dd * 4 + 1] * wv.y +
                 dl[dd * 4 + 2] * wv.z + dl[dd * 4 + 3] * wv.w;
        }
        atomicAdd(&orow[n], a);
    }
}

// ---------------------------------------------------------------------------
extern "C" void kernel_launch(void* const* d_in, const int* in_sizes, int n_in,
                              void* d_out, int out_size, void* d_ws, size_t ws_size,
                              hipStream_t stream)
{
    (void)in_sizes; (void)n_in; (void)out_size; (void)ws_size;
    const float* x     = (const float*)d_in[0];
    const float* ctxin = (const float*)d_in[1];
    const float* Wq    = (const float*)d_in[2];
    const float* bq    = (const float*)d_in[3];
    const float* Wk    = (const float*)d_in[4];
    const float* bk    = (const float*)d_in[5];
    const float* Wv    = (const float*)d_in[6];
    const float* bv    = (const float*)d_in[7];
    const float* Wo    = (const float*)d_in[8];
    const float* bo    = (const float*)d_in[9];
    const int*   idxs  = (const int*)d_in[10];
    float* out = (float*)d_out;

    char* ws = (char*)d_ws;
    size_t off = 0;
    auto alloc = [&](size_t bytes) -> void* {
        void* p = ws + off;
        off += (bytes + 255) & ~(size_t)255;
        return p;
    };

    const size_t qkv_bytes = (size_t)BATCH * NH * LSEQ * DHD * sizeof(float);
    float*         Qt       = (float*)alloc(qkv_bytes);
    float*         Kt       = (float*)alloc(qkv_bytes);
    float*         Vt       = (float*)alloc(qkv_bytes);
    float*         Mbuf     = (float*)alloc((size_t)BATCH * NH * LSEQ * sizeof(float));
    float*         VmeanRaw = (float*)alloc((size_t)BATCH * NH * DHD * sizeof(float));
    float*         meanout  = (float*)alloc((size_t)BATCH * DMODEL * sizeof(float));
    float*         delta    = (float*)alloc((size_t)BATCH * NH * NTOP * DHD * sizeof(float));
    int*           topidx   = (int*)alloc((size_t)BATCH * NH * NTOP * sizeof(int));
    unsigned*      headmask = (unsigned*)alloc((size_t)BATCH * LSEQ * sizeof(unsigned));
    unsigned char* slot     = (unsigned char*)alloc((size_t)BATCH * NH * LSEQ);
    float*         wsum     = (float*)alloc((size_t)BATCH * NH * NTOP * sizeof(float));
    float*         uacc     = (float*)alloc((size_t)BATCH * NH * NTOP * DHD * sizeof(float));
    u16*           xsP      = (u16*)alloc(ASTRIDE * 3 * 2);
    u16*           csP      = (u16*)alloc(ASTRIDE * 3 * 2);
    u16*           wqP      = (u16*)alloc(WSTRIDE * 3 * 2);
    u16*           wkP      = (u16*)alloc(WSTRIDE * 3 * 2);
    u16*           wvP      = (u16*)alloc(WSTRIDE * 3 * 2);

    split3_all<<<2048, 256, 0, stream>>>(x, ctxin, Wq, Wk, Wv,
                                         xsP, csP, wqP, wkP, wvP);

    gemm_mfma<3><<<dim3(256, 2), 256, 0, stream>>>(
        xsP, wqP, csP, wkP, bq, bk, Qt, Kt);

    // score right after QK gemm: Kt still L2-warm (2 MB/XCD)
    score_kernel<<<(BATCH * NH * LSEQ) / 4, 256, 0, stream>>>(
        Qt, Kt, idxs, Mbuf, headmask, VmeanRaw, uacc, wsum);

    topk_kernel<<<BATCH * NH, 256, 0, stream>>>(Mbuf, topidx, headmask, slot);

    gemm_mfma<2><<<dim3(256, 1), 256, 0, stream>>>(
        csP, wvP, csP, wvP, bv, bv, Vt, Vt);

    attn_partial<<<dim3(BATCH * NH, NSEG), 256, 0, stream>>>(
        Qt, Kt, Vt, topidx, wsum, uacc, VmeanRaw);

    finalize_kernel<<<324, 256, 0, stream>>>(
        wsum, uacc, VmeanRaw, Wo, bo, delta, meanout);

    out_base<<<2048, 256, 0, stream>>>(meanout, out);

    out_scatter<<<dim3(BATCH * NH, NTOP), 128, 0, stream>>>(
        topidx, delta, Wo, out);
}

// Round 15
// 261.346 us; speedup vs baseline: 1.2655x; 1.0737x over previous
//
#include <hip/hip_runtime.h>
#include <float.h>

#define BATCH 4
#define LSEQ  2048
#define DMODEL 512
#define NH    8
#define DHD   64
#define NSAMP 40
#define NTOP  40
#define NSEG  16                 // segs per bh; 16 * 128 = 2048 keys
#define SEGK  128                // keys per block
#define SUBK  64                 // keys per subtile
#define QK_SCALE 0.125f

typedef unsigned short u16;
typedef __attribute__((ext_vector_type(8))) short short8b;  // 8 bf16 = 16 B
typedef __attribute__((ext_vector_type(4))) float f32x4;
typedef __attribute__((ext_vector_type(4))) float f32x4v;

#define ASTRIDE ((size_t)BATCH * LSEQ * DMODEL)   // 4,194,304 elems (2^22)
#define WSTRIDE ((size_t)DMODEL * DMODEL)         //   262,144 elems (2^18)

// RTNE float->bf16 on raw bits (inputs finite).
static __device__ __forceinline__ u16 f2bf(float x) {
    unsigned u = __float_as_uint(x);
    u += 0x7FFFu + ((u >> 16) & 1u);
    return (u16)(u >> 16);
}
static __device__ __forceinline__ float bf2f(u16 s) {
    return __uint_as_float((unsigned)s << 16);
}
// float4 -> two bf16 planes (2-split): x = p1 + p2 + O(2^-17 |x|)
static __device__ __forceinline__ void split2(
    const float4 v, ushort4& o1, ushort4& o2)
{
    const float in[4] = {v.x, v.y, v.z, v.w};
    u16 a[4], b[4];
#pragma unroll
    for (int c = 0; c < 4; ++c) {
        a[c] = f2bf(in[c]);
        b[c] = f2bf(in[c] - bf2f(a[c]));
    }
    o1.x = a[0]; o1.y = a[1]; o1.z = a[2]; o1.w = a[3];
    o2.x = b[0]; o2.y = b[1]; o2.z = b[2]; o2.w = b[3];
}

// ---------------------------------------------------------------------------
// K0: unified 3-way bf16 split, ONE dispatch. x = p1+p2+p3 + O(2^-27|x|).
// ---------------------------------------------------------------------------
__global__ __launch_bounds__(256) void split3_all(
    const float* __restrict__ x, const float* __restrict__ ctxin,
    const float* __restrict__ Wq, const float* __restrict__ Wk,
    const float* __restrict__ Wv,
    u16* __restrict__ xsP, u16* __restrict__ csP,
    u16* __restrict__ wqP, u16* __restrict__ wkP, u16* __restrict__ wvP)
{
    const int X4 = 1 << 20;
    const int W4 = 1 << 16;
    const int total = 2 * X4 + 3 * W4;
    for (int i = blockIdx.x * 256 + threadIdx.x; i < total; i += gridDim.x * 256) {
        const float* src; u16* dst; size_t pstride; int i4;
        if (i < X4)            { src = x;     dst = xsP; pstride = ASTRIDE; i4 = i; }
        else if (i < 2 * X4)   { src = ctxin; dst = csP; pstride = ASTRIDE; i4 = i - X4; }
        else {
            const int w = i - 2 * X4;
            const int which = w >> 16, rem = w & (W4 - 1);
            src = (which == 0) ? Wq : (which == 1) ? Wk : Wv;
            dst = (which == 0) ? wqP : (which == 1) ? wkP : wvP;
            pstride = WSTRIDE; i4 = rem;
        }
        const float4 v = reinterpret_cast<const float4*>(src)[i4];
        const float in[4] = {v.x, v.y, v.z, v.w};
        ushort4 o1, o2, o3;
        u16 b1[4], b2[4], b3[4];
#pragma unroll
        for (int c = 0; c < 4; ++c) {
            const float xx = in[c];
            b1[c] = f2bf(xx);
            const float r1 = xx - bf2f(b1[c]);
            b2[c] = f2bf(r1);
            b3[c] = f2bf(r1 - bf2f(b2[c]));
        }
        o1.x = b1[0]; o1.y = b1[1]; o1.z = b1[2]; o1.w = b1[3];
        o2.x = b2[0]; o2.y = b2[1]; o2.z = b2[2]; o2.w = b2[3];
        o3.x = b3[0]; o3.y = b3[1]; o3.z = b3[2]; o3.w = b3[3];
        reinterpret_cast<ushort4*>(dst)[i4]                = o1;
        reinterpret_cast<ushort4*>(dst + pstride)[i4]      = o2;
        reinterpret_cast<ushort4*>(dst + 2 * pstride)[i4]  = o3;
    }
}

// ---------------------------------------------------------------------------
// K1: GEMM on MFMA, bf16xNP planes. NP=3 (Q,K): fp32-accuracy 6-product.
// NP=2 (V): 3-product, err ~1e-5 (V never feeds top-k). Tile 128x128.
// colsum != nullptr (V path): epilogue atomically accumulates per-(b,h,d)
// column sums (vmean fold-in — V already in registers here).
// ---------------------------------------------------------------------------
template<int NP>
__global__ __launch_bounds__(256) void gemm_mfma(
    const u16* __restrict__ A0, const u16* __restrict__ W0,
    const u16* __restrict__ A1, const u16* __restrict__ W1,
    const float* __restrict__ bias0, const float* __restrict__ bias1,
    float* __restrict__ Out0, float* __restrict__ Out1,
    float* __restrict__ colsum)
{
    const int z = blockIdx.y;
    const int i = blockIdx.x;
    const int xcd = i & 7;
    const int loc = i >> 3;
    const int m0 = (xcd * 8 + (loc & 7)) * 128;
    const int n0 = (loc >> 3) * 128;

    const u16* __restrict__ Ap   = z ? A1 : A0;
    const u16* __restrict__ Wp   = z ? W1 : W0;
    const float* __restrict__ bias = z ? bias1 : bias0;
    float*       __restrict__ Out  = z ? Out1 : Out0;

    __shared__ u16 As[NP][128][40];
    __shared__ u16 Ws[NP][128][40];

    const int tid  = threadIdx.x;
    const int w    = tid >> 6;
    const int lane = tid & 63;
    const int wm   = w >> 1;
    const int wn   = w & 1;
    const int lr   = lane & 15;
    const int lg   = lane >> 4;

    const int srow = tid >> 1;
    const int sc   = (tid & 1) * 16;

    f32x4 acc[4][4];
#pragma unroll
    for (int mf = 0; mf < 4; ++mf)
#pragma unroll
        for (int nf = 0; nf < 4; ++nf)
#pragma unroll
            for (int r = 0; r < 4; ++r) acc[mf][nf][r] = 0.f;

    short8b sa[NP][2], sw[NP][2];
#pragma unroll
    for (int p = 0; p < NP; ++p) {
        const u16* asrc = Ap + p * ASTRIDE + (size_t)(m0 + srow) * DMODEL + sc;
        const u16* wsrc = Wp + p * WSTRIDE + (size_t)(n0 + srow) * DMODEL + sc;
        sa[p][0] = *reinterpret_cast<const short8b*>(asrc);
        sa[p][1] = *reinterpret_cast<const short8b*>(asrc + 8);
        sw[p][0] = *reinterpret_cast<const short8b*>(wsrc);
        sw[p][1] = *reinterpret_cast<const short8b*>(wsrc + 8);
    }

    for (int k0 = 0; k0 < DMODEL; k0 += 32) {
#pragma unroll
        for (int p = 0; p < NP; ++p) {
            *reinterpret_cast<short8b*>(&As[p][srow][sc])     = sa[p][0];
            *reinterpret_cast<short8b*>(&As[p][srow][sc + 8]) = sa[p][1];
            *reinterpret_cast<short8b*>(&Ws[p][srow][sc])     = sw[p][0];
            *reinterpret_cast<short8b*>(&Ws[p][srow][sc + 8]) = sw[p][1];
        }
        __syncthreads();

        if (k0 + 32 < DMODEL) {
#pragma unroll
            for (int p = 0; p < NP; ++p) {
                const u16* asrc =
                    Ap + p * ASTRIDE + (size_t)(m0 + srow) * DMODEL + k0 + 32 + sc;
                const u16* wsrc =
                    Wp + p * WSTRIDE + (size_t)(n0 + srow) * DMODEL + k0 + 32 + sc;
                sa[p][0] = *reinterpret_cast<const short8b*>(asrc);
                sa[p][1] = *reinterpret_cast<const short8b*>(asrc + 8);
                sw[p][0] = *reinterpret_cast<const short8b*>(wsrc);
                sw[p][1] = *reinterpret_cast<const short8b*>(wsrc + 8);
            }
        }

        short8b af[4][NP];
#pragma unroll
        for (int mf = 0; mf < 4; ++mf) {
            const int row = wm * 64 + mf * 16 + lr;
#pragma unroll
            for (int p = 0; p < NP; ++p)
                af[mf][p] = *reinterpret_cast<const short8b*>(&As[p][row][lg * 8]);
        }
#pragma unroll
        for (int nf = 0; nf < 4; ++nf) {
            const int row = wn * 64 + nf * 16 + lr;
            const short8b b1 = *reinterpret_cast<const short8b*>(&Ws[0][row][lg * 8]);
            const short8b b2 = *reinterpret_cast<const short8b*>(&Ws[1][row][lg * 8]);
#pragma unroll
            for (int mf = 0; mf < 4; ++mf) {
                acc[mf][nf] = __builtin_amdgcn_mfma_f32_16x16x32_bf16(af[mf][0], b1, acc[mf][nf], 0, 0, 0);
                acc[mf][nf] = __builtin_amdgcn_mfma_f32_16x16x32_bf16(af[mf][1], b1, acc[mf][nf], 0, 0, 0);
                acc[mf][nf] = __builtin_amdgcn_mfma_f32_16x16x32_bf16(af[mf][0], b2, acc[mf][nf], 0, 0, 0);
                if constexpr (NP == 3) {
                    const short8b b3 = *reinterpret_cast<const short8b*>(&Ws[2][row][lg * 8]);
                    acc[mf][nf] = __builtin_amdgcn_mfma_f32_16x16x32_bf16(af[mf][2], b1, acc[mf][nf], 0, 0, 0);
                    acc[mf][nf] = __builtin_amdgcn_mfma_f32_16x16x32_bf16(af[mf][0], b3, acc[mf][nf], 0, 0, 0);
                    acc[mf][nf] = __builtin_amdgcn_mfma_f32_16x16x32_bf16(af[mf][1], b2, acc[mf][nf], 0, 0, 0);
                }
            }
        }
        __syncthreads();
    }

#pragma unroll
    for (int nf = 0; nf < 4; ++nf) {
        const int n = n0 + wn * 64 + nf * 16 + lr;
        const int h = n >> 6, d = n & 63;
        const float bv_ = bias[n];
        float cs = 0.f;
#pragma unroll
        for (int mf = 0; mf < 4; ++mf) {
#pragma unroll
            for (int r = 0; r < 4; ++r) {
                const int m = m0 + wm * 64 + mf * 16 + lg * 4 + r;
                const int b = m >> 11, l = m & (LSEQ - 1);
                const float val = acc[mf][nf][r] + bv_;
                Out[((size_t)(b * NH + h) * LSEQ + l) * DHD + d] = val;
                cs += val;
            }
        }
        if (colsum)
            atomicAdd(&colsum[((m0 >> 11) * NH + h) * DHD + d], cs);
    }
}

// ---------------------------------------------------------------------------
// K2: sampled sparsity measure + zero-init of headmask/VmeanRaw/uacc/wsum.
// Runs right after gemm<3>: Kt still L2-warm.
// ---------------------------------------------------------------------------
__global__ __launch_bounds__(256) void score_kernel(
    const float* __restrict__ Qt, const float* __restrict__ Kt,
    const int* __restrict__ idxs, float* __restrict__ M,
    unsigned* __restrict__ headmask, float* __restrict__ VmeanRaw,
    float* __restrict__ uacc, float* __restrict__ wsum)
{
    const int flat = blockIdx.x;
    if (flat < 32)        headmask[flat * 256 + threadIdx.x] = 0u;
    else if (flat < 40)   VmeanRaw[(flat - 32) * 256 + threadIdx.x] = 0.f;
    else if (flat < 360)  uacc[(flat - 40) * 256 + threadIdx.x] = 0.f;   // 81920
    else if (flat < 365) { const int j = (flat - 360) * 256 + threadIdx.x;
                           if (j < NH * BATCH * NTOP) wsum[j] = 0.f; }

    const int xcd  = flat & 7;
    const int slot = flat >> 3;
    const int bh   = xcd * 4 + (slot >> 9);
    const int w    = threadIdx.x >> 6;
    const int lane = threadIdx.x & 63;
    const int l    = (slot & 511) * 4 + w;

    const int g  = lane >> 4;
    const int dl = lane & 15;

#if defined(__has_builtin) && __has_builtin(__builtin_nontemporal_load)
    const f32x4v q4 = __builtin_nontemporal_load(
        reinterpret_cast<const f32x4v*>(Qt + ((size_t)bh * LSEQ + l) * DHD + dl * 4));
#else
    const f32x4v q4 = *reinterpret_cast<const f32x4v*>(
        Qt + ((size_t)bh * LSEQ + l) * DHD + dl * 4);
#endif

    const float* Kb = Kt + (size_t)bh * LSEQ * DHD;
    float vmax = -FLT_MAX, vsum = 0.f;
#pragma unroll
    for (int it = 0; it < 10; ++it) {
        const int s = it * 4 + g;
        const int ks = idxs[l * NSAMP + s];
        const float4 k4 = *reinterpret_cast<const float4*>(
            Kb + (size_t)ks * DHD + dl * 4);
        float p = q4[0] * k4.x + q4[1] * k4.y + q4[2] * k4.z + q4[3] * k4.w;
        p += __shfl_xor(p, 1);
        p += __shfl_xor(p, 2);
        p += __shfl_xor(p, 4);
        p += __shfl_xor(p, 8);
        vmax = fmaxf(vmax, p);
        vsum += p;
    }
    vmax = fmaxf(vmax, __shfl_xor(vmax, 16));
    vsum += __shfl_xor(vsum, 16);
    vmax = fmaxf(vmax, __shfl_xor(vmax, 32));
    vsum += __shfl_xor(vsum, 32);
    if (lane == 0) M[(size_t)bh * LSEQ + l] = vmax - vsum * (1.0f / LSEQ);
}

// ---------------------------------------------------------------------------
// K3: stable top-40 per (b,h); candidates in registers.
// ---------------------------------------------------------------------------
__global__ __launch_bounds__(256) void topk_kernel(
    const float* __restrict__ M, int* __restrict__ topidx,
    unsigned* __restrict__ headmask, unsigned char* __restrict__ slot)
{
    const int bh = blockIdx.x;
    const int b = bh >> 3, h = bh & 7;
    const int w = threadIdx.x >> 6, lane = threadIdx.x & 63;
    const int base = threadIdx.x * 8;

    float e[8];
    {
        const float4 v0 = *reinterpret_cast<const float4*>(M + (size_t)bh * LSEQ + base);
        const float4 v1 = *reinterpret_cast<const float4*>(M + (size_t)bh * LSEQ + base + 4);
        e[0] = v0.x; e[1] = v0.y; e[2] = v0.z; e[3] = v0.w;
        e[4] = v1.x; e[5] = v1.y; e[6] = v1.z; e[7] = v1.w;
    }

    __shared__ float rv[4];
    __shared__ int   ri[4];
    __shared__ int   winner;

    for (int t = 0; t < NTOP; ++t) {
        float bv = e[0]; int br = 0;
#pragma unroll
        for (int r = 1; r < 8; ++r)
            if (e[r] > bv) { bv = e[r]; br = r; }
        int bi = base + br;
#pragma unroll
        for (int off = 32; off; off >>= 1) {
            const float ov = __shfl_xor(bv, off);
            const int   oi = __shfl_xor(bi, off);
            if (ov > bv || (ov == bv && oi < bi)) { bv = ov; bi = oi; }
        }
        if (lane == 0) { rv[w] = bv; ri[w] = bi; }
        __syncthreads();
        if (threadIdx.x == 0) {
            float fv = rv[0]; int fi = ri[0];
#pragma unroll
            for (int k = 1; k < 4; ++k)
                if (rv[k] > fv || (rv[k] == fv && ri[k] < fi)) { fv = rv[k]; fi = ri[k]; }
            topidx[bh * NTOP + t] = fi;
            atomicOr(&headmask[b * LSEQ + fi], 1u << h);
            slot[bh * LSEQ + fi] = (unsigned char)t;
            winner = fi;
        }
        __syncthreads();
        const int fi = winner;
        if ((fi >> 3) == threadIdx.x) e[fi & 7] = -FLT_MAX;
    }
}

// ---------------------------------------------------------------------------
// K4: attention partials on MFMA (v6). Grid (32 bh, 16 segs of 128 keys).
// Q (40->48 rows) staged once as bf16 2-split; per 64-key subtile: K 2-split,
// V 2-split TRANSPOSED ([d][key] - B operand needs n=d rows); QK^T and PV
// via mfma_f32_16x16x32_bf16, 3 products (a1b1,a2b1,a1b2), err ~2e-5.
// P planes overwrite the Ks buffer (K dead after scores). PV accumulates in
// C registers across subtiles; single atomic flush. Replaces the VALU version
// that was LDS-BW-bound (650KB/chunk re-reads).
// ---------------------------------------------------------------------------
__global__ __launch_bounds__(256) void attn_partial(
    const float* __restrict__ Qt, const float* __restrict__ Kt,
    const float* __restrict__ Vt, const int* __restrict__ topidx,
    float* __restrict__ wsum, float* __restrict__ uacc)
{
    const int bh  = blockIdx.x;
    const int seg = blockIdx.y;
    const int tid = threadIdx.x;
    const int w    = tid >> 6;       // wave: QK -> k-tile, PV -> d-tile
    const int lane = tid & 63;
    const int lr = lane & 15, lg = lane >> 4;

    __shared__ u16 Qs[2][48][72];    // 13824 B  (2-split Q, rows 40..47 = 0)
    __shared__ u16 Ks[2][64][72];    // 18432 B  (K planes; reused for P)
    __shared__ u16 Vtl[2][64][72];   // 18432 B  (V^T planes: [d][key])
    __shared__ float wsl[48];        //   192 B  -> ~50.9 KB total

    // stage Q once (gathered rows; 48x16 float4 slots)
    for (int i = tid; i < 48 * 16; i += 256) {
        const int row = i >> 4, c = i & 15;
        float4 v = make_float4(0.f, 0.f, 0.f, 0.f);
        if (row < NTOP) {
            const int l = topidx[bh * NTOP + row];
            v = *reinterpret_cast<const float4*>(
                Qt + ((size_t)bh * LSEQ + l) * DHD + c * 4);
        }
        ushort4 o1, o2;
        split2(v, o1, o2);
        *reinterpret_cast<ushort4*>(&Qs[0][row][c * 4]) = o1;
        *reinterpret_cast<ushort4*>(&Qs[1][row][c * 4]) = o2;
    }
    if (tid < 48) wsl[tid] = 0.f;

    f32x4 pvacc[3];
#pragma unroll
    for (int qt = 0; qt < 3; ++qt)
#pragma unroll
        for (int r = 0; r < 4; ++r) pvacc[qt][r] = 0.f;

    for (int sub = 0; sub < 2; ++sub) {
        const int kbase = seg * SEGK + sub * SUBK;
        __syncthreads();                 // Qs ready / prev-subtile PV done

        // stage K (row-major) and V^T (transposed), both 2-split
        for (int i = tid; i < 64 * 16; i += 256) {
            const int key = i >> 4, c = i & 15;
            const size_t g = ((size_t)bh * LSEQ + kbase + key) * DHD + c * 4;
            const float4 kv = *reinterpret_cast<const float4*>(Kt + g);
            const float4 vv = *reinterpret_cast<const float4*>(Vt + g);
            ushort4 k1, k2, v1, v2;
            split2(kv, k1, k2);
            split2(vv, v1, v2);
            *reinterpret_cast<ushort4*>(&Ks[0][key][c * 4]) = k1;
            *reinterpret_cast<ushort4*>(&Ks[1][key][c * 4]) = k2;
            Vtl[0][c * 4 + 0][key] = v1.x; Vtl[0][c * 4 + 1][key] = v1.y;
            Vtl[0][c * 4 + 2][key] = v1.z; Vtl[0][c * 4 + 3][key] = v1.w;
            Vtl[1][c * 4 + 0][key] = v2.x; Vtl[1][c * 4 + 1][key] = v2.y;
            Vtl[1][c * 4 + 2][key] = v2.z; Vtl[1][c * 4 + 3][key] = v2.w;
        }
        __syncthreads();

        // QK^T: wave w -> k-tile w (cols w*16..w*16+15). M=48 q, Kdim=64.
        f32x4 acc[3];
#pragma unroll
        for (int qt = 0; qt < 3; ++qt)
#pragma unroll
            for (int r = 0; r < 4; ++r) acc[qt][r] = 0.f;
#pragma unroll
        for (int ks = 0; ks < 2; ++ks) {
            const short8b b1 = *reinterpret_cast<const short8b*>(
                &Ks[0][w * 16 + lr][ks * 32 + lg * 8]);
            const short8b b2 = *reinterpret_cast<const short8b*>(
                &Ks[1][w * 16 + lr][ks * 32 + lg * 8]);
#pragma unroll
            for (int qt = 0; qt < 3; ++qt) {
                const short8b a1 = *reinterpret_cast<const short8b*>(
                    &Qs[0][qt * 16 + lr][ks * 32 + lg * 8]);
                const short8b a2 = *reinterpret_cast<const short8b*>(
                    &Qs[1][qt * 16 + lr][ks * 32 + lg * 8]);
                acc[qt] = __builtin_amdgcn_mfma_f32_16x16x32_bf16(a1, b1, acc[qt], 0, 0, 0);
                acc[qt] = __builtin_amdgcn_mfma_f32_16x16x32_bf16(a2, b1, acc[qt], 0, 0, 0);
                acc[qt] = __builtin_amdgcn_mfma_f32_16x16x32_bf16(a1, b2, acc[qt], 0, 0, 0);
            }
        }
        __syncthreads();                 // all waves done reading Ks

        // exp + row-sums + write P planes into Ks (rows 0..47)
#pragma unroll
        for (int qt = 0; qt < 3; ++qt) {
#pragma unroll
            for (int r = 0; r < 4; ++r) {
                const float e = __expf(acc[qt][r] * QK_SCALE);
                float s = e;
                s += __shfl_xor(s, 1);
                s += __shfl_xor(s, 2);
                s += __shfl_xor(s, 4);
                s += __shfl_xor(s, 8);
                const int q = qt * 16 + lg * 4 + r;   // C row
                if (lr == 0) atomicAdd(&wsl[q], s);
                const u16 p1 = f2bf(e);
                const u16 p2 = f2bf(e - bf2f(p1));
                Ks[0][q][w * 16 + lr] = p1;           // C col = k
                Ks[1][q][w * 16 + lr] = p2;
            }
        }
        __syncthreads();

        // PV: wave w -> d-tile w. A = P (rows q), B = V^T (rows d). Kdim=64.
#pragma unroll
        for (int ks = 0; ks < 2; ++ks) {
            const short8b b1 = *reinterpret_cast<const short8b*>(
                &Vtl[0][w * 16 + lr][ks * 32 + lg * 8]);
            const short8b b2 = *reinterpret_cast<const short8b*>(
                &Vtl[1][w * 16 + lr][ks * 32 + lg * 8]);
#pragma unroll
            for (int qt = 0; qt < 3; ++qt) {
                const short8b a1 = *reinterpret_cast<const short8b*>(
                    &Ks[0][qt * 16 + lr][ks * 32 + lg * 8]);
                const short8b a2 = *reinterpret_cast<const short8b*>(
                    &Ks[1][qt * 16 + lr][ks * 32 + lg * 8]);
                pvacc[qt] = __builtin_amdgcn_mfma_f32_16x16x32_bf16(a1, b1, pvacc[qt], 0, 0, 0);
                pvacc[qt] = __builtin_amdgcn_mfma_f32_16x16x32_bf16(a2, b1, pvacc[qt], 0, 0, 0);
                pvacc[qt] = __builtin_amdgcn_mfma_f32_16x16x32_bf16(a1, b2, pvacc[qt], 0, 0, 0);
            }
        }
    }

    // flush: uacc (C col = d = w*16+lr, row = q), wsum
#pragma unroll
    for (int qt = 0; qt < 3; ++qt) {
#pragma unroll
        for (int r = 0; r < 4; ++r) {
            const int q = qt * 16 + lg * 4 + r;
            if (q < NTOP)
                atomicAdd(&uacc[((size_t)bh * NTOP + q) * DHD + w * 16 + lr],
                          pvacc[qt][r]);
        }
    }
    if (tid < NTOP) atomicAdd(&wsum[bh * NTOP + tid], wsl[tid]);
}

// ---------------------------------------------------------------------------
// K5: finalize — delta = uacc/wsum - vmean (flat), + 4 meanout blocks.
// ---------------------------------------------------------------------------
__global__ __launch_bounds__(256) void finalize_kernel(
    const float* __restrict__ wsum, const float* __restrict__ uacc,
    const float* __restrict__ VmeanRaw, const float* __restrict__ Wo,
    const float* __restrict__ bo, float* __restrict__ delta,
    float* __restrict__ meanout)
{
    const int blk = blockIdx.x;
    if (blk < 320) {
        const int idx = blk * 256 + threadIdx.x;
        const int bh = idx / 2560;
        const int rem = idx - bh * 2560;
        const int q = rem >> 6, d = rem & 63;
        const float vm = VmeanRaw[bh * DHD + d] * (1.0f / (float)LSEQ);
        delta[idx] = uacc[idx] / wsum[bh * NTOP + q] - vm;
    } else {
        const int b = blk - 320;
        __shared__ float mc[DMODEL];
        for (int i = threadIdx.x; i < DMODEL; i += 256)
            mc[i] = VmeanRaw[b * DMODEL + i] * (1.0f / (float)LSEQ);
        __syncthreads();
        for (int n = threadIdx.x; n < DMODEL; n += 256) {
            float acc = bo[n];
            const float* wr = Wo + (size_t)n * DMODEL;
            for (int k = 0; k < DMODEL; ++k) acc = fmaf(mc[k], wr[k], acc);
            meanout[b * DMODEL + n] = acc;
        }
    }
}

// ---------------------------------------------------------------------------
// K6a: broadcast mean rows to ALL output rows (pure streaming write).
// ---------------------------------------------------------------------------
__global__ __launch_bounds__(256) void out_base(
    const float* __restrict__ meanout, float* __restrict__ out)
{
    const int total4 = BATCH * LSEQ * (DMODEL / 4);
    for (int i = blockIdx.x * 256 + threadIdx.x; i < total4; i += gridDim.x * 256) {
        const int row = i >> 7;
        const int b = row >> 11;
        const int c = i & 127;
        reinterpret_cast<float4*>(out)[i] =
            reinterpret_cast<const float4*>(meanout)[b * 128 + c];
    }
}

// ---------------------------------------------------------------------------
// K6b: scatter-add selected rows: out[b,l,:] += delta[bh,u] @ Wo_h^T.
// ---------------------------------------------------------------------------
__global__ __launch_bounds__(128) void out_scatter(
    const int* __restrict__ topidx, const float* __restrict__ delta,
    const float* __restrict__ Wo, float* __restrict__ out)
{
    const int bh = blockIdx.x;
    const int u  = blockIdx.y;
    const int b = bh >> 3, h = bh & 7;
    const int l = topidx[bh * NTOP + u];

    __shared__ float dl[DHD];
    if (threadIdx.x < DHD)
        dl[threadIdx.x] = delta[((size_t)bh * NTOP + u) * DHD + threadIdx.x];
    __syncthreads();

    float* orow = out + ((size_t)b * LSEQ + l) * DMODEL;
#pragma unroll
    for (int c = 0; c < 4; ++c) {
        const int n = threadIdx.x * 4 + c;
        const float4* wr4 = reinterpret_cast<const float4*>(
            Wo + (size_t)n * DMODEL + h * DHD);
        float a = 0.f;
#pragma unroll
        for (int dd = 0; dd < 16; ++dd) {
            const float4 wv = wr4[dd];
            a += dl[dd * 4 + 0] * wv.x + dl[dd * 4 + 1] * wv.y +
                 dl[dd * 4 + 2] * wv.z + dl[dd * 4 + 3] * wv.w;
        }
        atomicAdd(&orow[n], a);
    }
}

// ---------------------------------------------------------------------------
extern "C" void kernel_launch(void* const* d_in, const int* in_sizes, int n_in,
                              void* d_out, int out_size, void* d_ws, size_t ws_size,
                              hipStream_t stream)
{
    (void)in_sizes; (void)n_in; (void)out_size; (void)ws_size;
    const float* x     = (const float*)d_in[0];
    const float* ctxin = (const float*)d_in[1];
    const float* Wq    = (const float*)d_in[2];
    const float* bq    = (const float*)d_in[3];
    const float* Wk    = (const float*)d_in[4];
    const float* bk    = (const float*)d_in[5];
    const float* Wv    = (const float*)d_in[6];
    const float* bv    = (const float*)d_in[7];
    const float* Wo    = (const float*)d_in[8];
    const float* bo    = (const float*)d_in[9];
    const int*   idxs  = (const int*)d_in[10];
    float* out = (float*)d_out;

    char* ws = (char*)d_ws;
    size_t off = 0;
    auto alloc = [&](size_t bytes) -> void* {
        void* p = ws + off;
        off += (bytes + 255) & ~(size_t)255;
        return p;
    };

    const size_t qkv_bytes = (size_t)BATCH * NH * LSEQ * DHD * sizeof(float);
    float*         Qt       = (float*)alloc(qkv_bytes);
    float*         Kt       = (float*)alloc(qkv_bytes);
    float*         Vt       = (float*)alloc(qkv_bytes);
    float*         Mbuf     = (float*)alloc((size_t)BATCH * NH * LSEQ * sizeof(float));
    float*         VmeanRaw = (float*)alloc((size_t)BATCH * NH * DHD * sizeof(float));
    float*         meanout  = (float*)alloc((size_t)BATCH * DMODEL * sizeof(float));
    float*         delta    = (float*)alloc((size_t)BATCH * NH * NTOP * DHD * sizeof(float));
    int*           topidx   = (int*)alloc((size_t)BATCH * NH * NTOP * sizeof(int));
    unsigned*      headmask = (unsigned*)alloc((size_t)BATCH * LSEQ * sizeof(unsigned));
    unsigned char* slot     = (unsigned char*)alloc((size_t)BATCH * NH * LSEQ);
    float*         wsum     = (float*)alloc((size_t)BATCH * NH * NTOP * sizeof(float));
    float*         uacc     = (float*)alloc((size_t)BATCH * NH * NTOP * DHD * sizeof(float));
    u16*           xsP      = (u16*)alloc(ASTRIDE * 3 * 2);
    u16*           csP      = (u16*)alloc(ASTRIDE * 3 * 2);
    u16*           wqP      = (u16*)alloc(WSTRIDE * 3 * 2);
    u16*           wkP      = (u16*)alloc(WSTRIDE * 3 * 2);
    u16*           wvP      = (u16*)alloc(WSTRIDE * 3 * 2);

    split3_all<<<2048, 256, 0, stream>>>(x, ctxin, Wq, Wk, Wv,
                                         xsP, csP, wqP, wkP, wvP);

    gemm_mfma<3><<<dim3(256, 2), 256, 0, stream>>>(
        xsP, wqP, csP, wkP, bq, bk, Qt, Kt, nullptr);

    // score right after QK gemm: Kt still L2-warm; also zero-inits accums
    score_kernel<<<(BATCH * NH * LSEQ) / 4, 256, 0, stream>>>(
        Qt, Kt, idxs, Mbuf, headmask, VmeanRaw, uacc, wsum);

    topk_kernel<<<BATCH * NH, 256, 0, stream>>>(Mbuf, topidx, headmask, slot);

    // V gemm AFTER score (VmeanRaw zeroed there); colsum epilogue folds vmean
    gemm_mfma<2><<<dim3(256, 1), 256, 0, stream>>>(
        csP, wvP, csP, wvP, bv, bv, Vt, Vt, VmeanRaw);

    attn_partial<<<dim3(BATCH * NH, NSEG), 256, 0, stream>>>(
        Qt, Kt, Vt, topidx, wsum, uacc);

    finalize_kernel<<<324, 256, 0, stream>>>(
        wsum, uacc, VmeanRaw, Wo, bo, delta, meanout);

    out_base<<<2048, 256, 0, stream>>>(meanout, out);

    out_scatter<<<dim3(BATCH * NH, NTOP), 128, 0, stream>>>(
        topidx, delta, Wo, out);
}

// Round 16
// 224.617 us; speedup vs baseline: 1.4724x; 1.1635x over previous
//
#include <hip/hip_runtime.h>
#include <float.h>

#define BATCH 4
#define LSEQ  2048
#define DMODEL 512
#define NH    8
#define DHD   64
#define NSAMP 40
#define NTOP  40
#define NSEG  16                 // segs per bh; 16 * 128 = 2048 keys
#define SEGK  128                // keys per block
#define SUBK  64                 // keys per subtile
#define QK_SCALE 0.125f

typedef unsigned short u16;
typedef __attribute__((ext_vector_type(8))) short short8b;  // 8 bf16 = 16 B
typedef __attribute__((ext_vector_type(4))) float f32x4;
typedef __attribute__((ext_vector_type(4))) float f32x4v;

#define ASTRIDE ((size_t)BATCH * LSEQ * DMODEL)   // 4,194,304 elems (2^22)
#define WSTRIDE ((size_t)DMODEL * DMODEL)         //   262,144 elems (2^18)

// RTNE float->bf16 on raw bits (inputs finite).
static __device__ __forceinline__ u16 f2bf(float x) {
    unsigned u = __float_as_uint(x);
    u += 0x7FFFu + ((u >> 16) & 1u);
    return (u16)(u >> 16);
}
static __device__ __forceinline__ float bf2f(u16 s) {
    return __uint_as_float((unsigned)s << 16);
}
// float4 -> two bf16 planes (2-split): x = p1 + p2 + O(2^-17 |x|)
static __device__ __forceinline__ void split2(
    const float4 v, ushort4& o1, ushort4& o2)
{
    const float in[4] = {v.x, v.y, v.z, v.w};
    u16 a[4], b[4];
#pragma unroll
    for (int c = 0; c < 4; ++c) {
        a[c] = f2bf(in[c]);
        b[c] = f2bf(in[c] - bf2f(a[c]));
    }
    o1.x = a[0]; o1.y = a[1]; o1.z = a[2]; o1.w = a[3];
    o2.x = b[0]; o2.y = b[1]; o2.z = b[2]; o2.w = b[3];
}

// ---------------------------------------------------------------------------
// K0: unified 3-way bf16 split + zero-init of VmeanRaw/uacc/wsum (the inits
// that used to ride in score_kernel; must precede gemm_all's colsum atomics).
// ---------------------------------------------------------------------------
__global__ __launch_bounds__(256) void split3_all(
    const float* __restrict__ x, const float* __restrict__ ctxin,
    const float* __restrict__ Wq, const float* __restrict__ Wk,
    const float* __restrict__ Wv,
    u16* __restrict__ xsP, u16* __restrict__ csP,
    u16* __restrict__ wqP, u16* __restrict__ wkP, u16* __restrict__ wvP,
    float* __restrict__ VmeanRaw, float* __restrict__ uacc,
    float* __restrict__ wsum)
{
    const int flat = blockIdx.x;
    if (flat < 8)         VmeanRaw[flat * 256 + threadIdx.x] = 0.f;      // 2048
    else if (flat < 328)  uacc[(flat - 8) * 256 + threadIdx.x] = 0.f;    // 81920
    else if (flat < 333) { const int j = (flat - 328) * 256 + threadIdx.x;
                           if (j < BATCH * NH * NTOP) wsum[j] = 0.f; }

    const int X4 = 1 << 20;
    const int W4 = 1 << 16;
    const int total = 2 * X4 + 3 * W4;
    for (int i = blockIdx.x * 256 + threadIdx.x; i < total; i += gridDim.x * 256) {
        const float* src; u16* dst; size_t pstride; int i4;
        if (i < X4)            { src = x;     dst = xsP; pstride = ASTRIDE; i4 = i; }
        else if (i < 2 * X4)   { src = ctxin; dst = csP; pstride = ASTRIDE; i4 = i - X4; }
        else {
            const int w = i - 2 * X4;
            const int which = w >> 16, rem = w & (W4 - 1);
            src = (which == 0) ? Wq : (which == 1) ? Wk : Wv;
            dst = (which == 0) ? wqP : (which == 1) ? wkP : wvP;
            pstride = WSTRIDE; i4 = rem;
        }
        const float4 v = reinterpret_cast<const float4*>(src)[i4];
        const float in[4] = {v.x, v.y, v.z, v.w};
        ushort4 o1, o2, o3;
        u16 b1[4], b2[4], b3[4];
#pragma unroll
        for (int c = 0; c < 4; ++c) {
            const float xx = in[c];
            b1[c] = f2bf(xx);
            const float r1 = xx - bf2f(b1[c]);
            b2[c] = f2bf(r1);
            b3[c] = f2bf(r1 - bf2f(b2[c]));
        }
        o1.x = b1[0]; o1.y = b1[1]; o1.z = b1[2]; o1.w = b1[3];
        o2.x = b2[0]; o2.y = b2[1]; o2.z = b2[2]; o2.w = b2[3];
        o3.x = b3[0]; o3.y = b3[1]; o3.z = b3[2]; o3.w = b3[3];
        reinterpret_cast<ushort4*>(dst)[i4]                = o1;
        reinterpret_cast<ushort4*>(dst + pstride)[i4]      = o2;
        reinterpret_cast<ushort4*>(dst + 2 * pstride)[i4]  = o3;
    }
}

// ---------------------------------------------------------------------------
// K1: unified QKV GEMM, ONE dispatch, grid (256, 3). z=0 Q, z=1 K (3-plane,
// 6-product, fp32-accuracy — feeds top-k), z=2 V (2-plane, 3-product, err
// ~1e-5 + colsum epilogue for vmean). Plane loops manually unrolled with
// `if (p < npl)` guards — static indices, no scratch (rule #20). Fusing
// fixes V-gemm's former 1-block/CU solo round: 768 blocks at 2/CU.
// ---------------------------------------------------------------------------
__global__ __launch_bounds__(256) void gemm_all(
    const u16* __restrict__ xsP, const u16* __restrict__ csP,
    const u16* __restrict__ wqP, const u16* __restrict__ wkP,
    const u16* __restrict__ wvP,
    const float* __restrict__ bq, const float* __restrict__ bk,
    const float* __restrict__ bv,
    float* __restrict__ Qt, float* __restrict__ Kt, float* __restrict__ Vt,
    float* __restrict__ VmeanRaw)
{
    const int z = blockIdx.y;
    const int i = blockIdx.x;
    const int xcd = i & 7;
    const int loc = i >> 3;
    const int m0 = (xcd * 8 + (loc & 7)) * 128;
    const int n0 = (loc >> 3) * 128;

    const u16* __restrict__ Ap   = (z == 0) ? xsP : csP;
    const u16* __restrict__ Wp   = (z == 0) ? wqP : (z == 1 ? wkP : wvP);
    const float* __restrict__ bias = (z == 0) ? bq : (z == 1 ? bk : bv);
    float*       __restrict__ Out  = (z == 0) ? Qt : (z == 1 ? Kt : Vt);
    const int npl = (z == 2) ? 2 : 3;

    __shared__ u16 As[3][128][40];
    __shared__ u16 Ws[3][128][40];

    const int tid  = threadIdx.x;
    const int w    = tid >> 6;
    const int lane = tid & 63;
    const int wm   = w >> 1;
    const int wn   = w & 1;
    const int lr   = lane & 15;
    const int lg   = lane >> 4;

    const int srow = tid >> 1;
    const int sc   = (tid & 1) * 16;

    f32x4 acc[4][4];
#pragma unroll
    for (int mf = 0; mf < 4; ++mf)
#pragma unroll
        for (int nf = 0; nf < 4; ++nf)
#pragma unroll
            for (int r = 0; r < 4; ++r) acc[mf][nf][r] = 0.f;

    short8b sa[3][2], sw[3][2];
#pragma unroll
    for (int p = 0; p < 3; ++p) {
        if (p < npl) {
            const u16* asrc = Ap + p * ASTRIDE + (size_t)(m0 + srow) * DMODEL + sc;
            const u16* wsrc = Wp + p * WSTRIDE + (size_t)(n0 + srow) * DMODEL + sc;
            sa[p][0] = *reinterpret_cast<const short8b*>(asrc);
            sa[p][1] = *reinterpret_cast<const short8b*>(asrc + 8);
            sw[p][0] = *reinterpret_cast<const short8b*>(wsrc);
            sw[p][1] = *reinterpret_cast<const short8b*>(wsrc + 8);
        }
    }

    for (int k0 = 0; k0 < DMODEL; k0 += 32) {
#pragma unroll
        for (int p = 0; p < 3; ++p) {
            if (p < npl) {
                *reinterpret_cast<short8b*>(&As[p][srow][sc])     = sa[p][0];
                *reinterpret_cast<short8b*>(&As[p][srow][sc + 8]) = sa[p][1];
                *reinterpret_cast<short8b*>(&Ws[p][srow][sc])     = sw[p][0];
                *reinterpret_cast<short8b*>(&Ws[p][srow][sc + 8]) = sw[p][1];
            }
        }
        __syncthreads();

        if (k0 + 32 < DMODEL) {
#pragma unroll
            for (int p = 0; p < 3; ++p) {
                if (p < npl) {
                    const u16* asrc =
                        Ap + p * ASTRIDE + (size_t)(m0 + srow) * DMODEL + k0 + 32 + sc;
                    const u16* wsrc =
                        Wp + p * WSTRIDE + (size_t)(n0 + srow) * DMODEL + k0 + 32 + sc;
                    sa[p][0] = *reinterpret_cast<const short8b*>(asrc);
                    sa[p][1] = *reinterpret_cast<const short8b*>(asrc + 8);
                    sw[p][0] = *reinterpret_cast<const short8b*>(wsrc);
                    sw[p][1] = *reinterpret_cast<const short8b*>(wsrc + 8);
                }
            }
        }

        short8b af[4][3];
#pragma unroll
        for (int mf = 0; mf < 4; ++mf) {
            const int row = wm * 64 + mf * 16 + lr;
#pragma unroll
            for (int p = 0; p < 3; ++p)
                if (p < npl)
                    af[mf][p] = *reinterpret_cast<const short8b*>(&As[p][row][lg * 8]);
        }
#pragma unroll
        for (int nf = 0; nf < 4; ++nf) {
            const int row = wn * 64 + nf * 16 + lr;
            const short8b b1 = *reinterpret_cast<const short8b*>(&Ws[0][row][lg * 8]);
            const short8b b2 = *reinterpret_cast<const short8b*>(&Ws[1][row][lg * 8]);
#pragma unroll
            for (int mf = 0; mf < 4; ++mf) {
                acc[mf][nf] = __builtin_amdgcn_mfma_f32_16x16x32_bf16(af[mf][0], b1, acc[mf][nf], 0, 0, 0);
                acc[mf][nf] = __builtin_amdgcn_mfma_f32_16x16x32_bf16(af[mf][1], b1, acc[mf][nf], 0, 0, 0);
                acc[mf][nf] = __builtin_amdgcn_mfma_f32_16x16x32_bf16(af[mf][0], b2, acc[mf][nf], 0, 0, 0);
            }
            if (z != 2) {
                const short8b b3 = *reinterpret_cast<const short8b*>(&Ws[2][row][lg * 8]);
#pragma unroll
                for (int mf = 0; mf < 4; ++mf) {
                    acc[mf][nf] = __builtin_amdgcn_mfma_f32_16x16x32_bf16(af[mf][2], b1, acc[mf][nf], 0, 0, 0);
                    acc[mf][nf] = __builtin_amdgcn_mfma_f32_16x16x32_bf16(af[mf][0], b3, acc[mf][nf], 0, 0, 0);
                    acc[mf][nf] = __builtin_amdgcn_mfma_f32_16x16x32_bf16(af[mf][1], b2, acc[mf][nf], 0, 0, 0);
                }
            }
        }
        __syncthreads();
    }

#pragma unroll
    for (int nf = 0; nf < 4; ++nf) {
        const int n = n0 + wn * 64 + nf * 16 + lr;
        const int h = n >> 6, d = n & 63;
        const float bv_ = bias[n];
        float cs = 0.f;
#pragma unroll
        for (int mf = 0; mf < 4; ++mf) {
#pragma unroll
            for (int r = 0; r < 4; ++r) {
                const int m = m0 + wm * 64 + mf * 16 + lg * 4 + r;
                const int b = m >> 11, l = m & (LSEQ - 1);
                const float val = acc[mf][nf][r] + bv_;
                Out[((size_t)(b * NH + h) * LSEQ + l) * DHD + d] = val;
                cs += val;
            }
        }
        if (z == 2)
            atomicAdd(&VmeanRaw[((m0 >> 11) * NH + h) * DHD + d], cs);
    }
}

// ---------------------------------------------------------------------------
// K2: sampled sparsity measure. Runs right after gemm_all: Kt L2-warm.
// ---------------------------------------------------------------------------
__global__ __launch_bounds__(256) void score_kernel(
    const float* __restrict__ Qt, const float* __restrict__ Kt,
    const int* __restrict__ idxs, float* __restrict__ M)
{
    const int flat = blockIdx.x;
    const int xcd  = flat & 7;
    const int slot = flat >> 3;
    const int bh   = xcd * 4 + (slot >> 9);
    const int w    = threadIdx.x >> 6;
    const int lane = threadIdx.x & 63;
    const int l    = (slot & 511) * 4 + w;

    const int g  = lane >> 4;
    const int dl = lane & 15;

#if defined(__has_builtin) && __has_builtin(__builtin_nontemporal_load)
    const f32x4v q4 = __builtin_nontemporal_load(
        reinterpret_cast<const f32x4v*>(Qt + ((size_t)bh * LSEQ + l) * DHD + dl * 4));
#else
    const f32x4v q4 = *reinterpret_cast<const f32x4v*>(
        Qt + ((size_t)bh * LSEQ + l) * DHD + dl * 4);
#endif

    const float* Kb = Kt + (size_t)bh * LSEQ * DHD;
    float vmax = -FLT_MAX, vsum = 0.f;
#pragma unroll
    for (int it = 0; it < 10; ++it) {
        const int s = it * 4 + g;
        const int ks = idxs[l * NSAMP + s];
        const float4 k4 = *reinterpret_cast<const float4*>(
            Kb + (size_t)ks * DHD + dl * 4);
        float p = q4[0] * k4.x + q4[1] * k4.y + q4[2] * k4.z + q4[3] * k4.w;
        p += __shfl_xor(p, 1);
        p += __shfl_xor(p, 2);
        p += __shfl_xor(p, 4);
        p += __shfl_xor(p, 8);
        vmax = fmaxf(vmax, p);
        vsum += p;
    }
    vmax = fmaxf(vmax, __shfl_xor(vmax, 16));
    vsum += __shfl_xor(vsum, 16);
    vmax = fmaxf(vmax, __shfl_xor(vmax, 32));
    vsum += __shfl_xor(vsum, 32);
    if (lane == 0) M[(size_t)bh * LSEQ + l] = vmax - vsum * (1.0f / LSEQ);
}

// ---------------------------------------------------------------------------
// K3: stable top-40 per (b,h) (blocks 0..31) + per-batch meanout (blocks
// 32..35 — VmeanRaw complete after gemm_all). headmask/slot removed: dead
// since the out_base/out_scatter split.
// ---------------------------------------------------------------------------
__global__ __launch_bounds__(256) void topk_kernel(
    const float* __restrict__ M, int* __restrict__ topidx,
    const float* __restrict__ VmeanRaw, const float* __restrict__ Wo,
    const float* __restrict__ bo, float* __restrict__ meanout)
{
    const int bh = blockIdx.x;

    if (bh >= 32) {                        // meanout for batch b
        const int b = bh - 32;
        __shared__ float mc[DMODEL];
        for (int i = threadIdx.x; i < DMODEL; i += 256)
            mc[i] = VmeanRaw[b * DMODEL + i] * (1.0f / (float)LSEQ);
        __syncthreads();
        for (int n = threadIdx.x; n < DMODEL; n += 256) {
            float acc = bo[n];
            const float* wr = Wo + (size_t)n * DMODEL;
            for (int k = 0; k < DMODEL; ++k) acc = fmaf(mc[k], wr[k], acc);
            meanout[b * DMODEL + n] = acc;
        }
        return;
    }

    const int w = threadIdx.x >> 6, lane = threadIdx.x & 63;
    const int base = threadIdx.x * 8;

    float e[8];
    {
        const float4 v0 = *reinterpret_cast<const float4*>(M + (size_t)bh * LSEQ + base);
        const float4 v1 = *reinterpret_cast<const float4*>(M + (size_t)bh * LSEQ + base + 4);
        e[0] = v0.x; e[1] = v0.y; e[2] = v0.z; e[3] = v0.w;
        e[4] = v1.x; e[5] = v1.y; e[6] = v1.z; e[7] = v1.w;
    }

    __shared__ float rv[4];
    __shared__ int   ri[4];
    __shared__ int   winner;

    for (int t = 0; t < NTOP; ++t) {
        float bv = e[0]; int br = 0;
#pragma unroll
        for (int r = 1; r < 8; ++r)
            if (e[r] > bv) { bv = e[r]; br = r; }
        int bi = base + br;
#pragma unroll
        for (int off = 32; off; off >>= 1) {
            const float ov = __shfl_xor(bv, off);
            const int   oi = __shfl_xor(bi, off);
            if (ov > bv || (ov == bv && oi < bi)) { bv = ov; bi = oi; }
        }
        if (lane == 0) { rv[w] = bv; ri[w] = bi; }
        __syncthreads();
        if (threadIdx.x == 0) {
            float fv = rv[0]; int fi = ri[0];
#pragma unroll
            for (int k = 1; k < 4; ++k)
                if (rv[k] > fv || (rv[k] == fv && ri[k] < fi)) { fv = rv[k]; fi = ri[k]; }
            topidx[bh * NTOP + t] = fi;
            winner = fi;
        }
        __syncthreads();
        const int fi = winner;
        if ((fi >> 3) == threadIdx.x) e[fi & 7] = -FLT_MAX;
    }
}

// ---------------------------------------------------------------------------
// K4: attention partials on MFMA. Grid (32 bh, 16 segs of 128 keys).
// Q (40->48) staged once as bf16 2-split; per 64-key subtile: K 2-split,
// V 2-split transposed; QK^T and PV via mfma_f32_16x16x32_bf16 (3 products,
// err ~2e-5). P planes overwrite Ks. PV accumulates in C registers; single
// atomic flush.
// ---------------------------------------------------------------------------
__global__ __launch_bounds__(256) void attn_partial(
    const float* __restrict__ Qt, const float* __restrict__ Kt,
    const float* __restrict__ Vt, const int* __restrict__ topidx,
    float* __restrict__ wsum, float* __restrict__ uacc)
{
    const int bh  = blockIdx.x;
    const int seg = blockIdx.y;
    const int tid = threadIdx.x;
    const int w    = tid >> 6;
    const int lane = tid & 63;
    const int lr = lane & 15, lg = lane >> 4;

    __shared__ u16 Qs[2][48][72];
    __shared__ u16 Ks[2][64][72];
    __shared__ u16 Vtl[2][64][72];
    __shared__ float wsl[48];

    for (int i = tid; i < 48 * 16; i += 256) {
        const int row = i >> 4, c = i & 15;
        float4 v = make_float4(0.f, 0.f, 0.f, 0.f);
        if (row < NTOP) {
            const int l = topidx[bh * NTOP + row];
            v = *reinterpret_cast<const float4*>(
                Qt + ((size_t)bh * LSEQ + l) * DHD + c * 4);
        }
        ushort4 o1, o2;
        split2(v, o1, o2);
        *reinterpret_cast<ushort4*>(&Qs[0][row][c * 4]) = o1;
        *reinterpret_cast<ushort4*>(&Qs[1][row][c * 4]) = o2;
    }
    if (tid < 48) wsl[tid] = 0.f;

    f32x4 pvacc[3];
#pragma unroll
    for (int qt = 0; qt < 3; ++qt)
#pragma unroll
        for (int r = 0; r < 4; ++r) pvacc[qt][r] = 0.f;

    for (int sub = 0; sub < 2; ++sub) {
        const int kbase = seg * SEGK + sub * SUBK;
        __syncthreads();

        for (int i = tid; i < 64 * 16; i += 256) {
            const int key = i >> 4, c = i & 15;
            const size_t g = ((size_t)bh * LSEQ + kbase + key) * DHD + c * 4;
            const float4 kv = *reinterpret_cast<const float4*>(Kt + g);
            const float4 vv = *reinterpret_cast<const float4*>(Vt + g);
            ushort4 k1, k2, v1, v2;
            split2(kv, k1, k2);
            split2(vv, v1, v2);
            *reinterpret_cast<ushort4*>(&Ks[0][key][c * 4]) = k1;
            *reinterpret_cast<ushort4*>(&Ks[1][key][c * 4]) = k2;
            Vtl[0][c * 4 + 0][key] = v1.x; Vtl[0][c * 4 + 1][key] = v1.y;
            Vtl[0][c * 4 + 2][key] = v1.z; Vtl[0][c * 4 + 3][key] = v1.w;
            Vtl[1][c * 4 + 0][key] = v2.x; Vtl[1][c * 4 + 1][key] = v2.y;
            Vtl[1][c * 4 + 2][key] = v2.z; Vtl[1][c * 4 + 3][key] = v2.w;
        }
        __syncthreads();

        f32x4 acc[3];
#pragma unroll
        for (int qt = 0; qt < 3; ++qt)
#pragma unroll
            for (int r = 0; r < 4; ++r) acc[qt][r] = 0.f;
#pragma unroll
        for (int ks = 0; ks < 2; ++ks) {
            const short8b b1 = *reinterpret_cast<const short8b*>(
                &Ks[0][w * 16 + lr][ks * 32 + lg * 8]);
            const short8b b2 = *reinterpret_cast<const short8b*>(
                &Ks[1][w * 16 + lr][ks * 32 + lg * 8]);
#pragma unroll
            for (int qt = 0; qt < 3; ++qt) {
                const short8b a1 = *reinterpret_cast<const short8b*>(
                    &Qs[0][qt * 16 + lr][ks * 32 + lg * 8]);
                const short8b a2 = *reinterpret_cast<const short8b*>(
                    &Qs[1][qt * 16 + lr][ks * 32 + lg * 8]);
                acc[qt] = __builtin_amdgcn_mfma_f32_16x16x32_bf16(a1, b1, acc[qt], 0, 0, 0);
                acc[qt] = __builtin_amdgcn_mfma_f32_16x16x32_bf16(a2, b1, acc[qt], 0, 0, 0);
                acc[qt] = __builtin_amdgcn_mfma_f32_16x16x32_bf16(a1, b2, acc[qt], 0, 0, 0);
            }
        }
        __syncthreads();

#pragma unroll
        for (int qt = 0; qt < 3; ++qt) {
#pragma unroll
            for (int r = 0; r < 4; ++r) {
                const float e = __expf(acc[qt][r] * QK_SCALE);
                float s = e;
                s += __shfl_xor(s, 1);
                s += __shfl_xor(s, 2);
                s += __shfl_xor(s, 4);
                s += __shfl_xor(s, 8);
                const int q = qt * 16 + lg * 4 + r;
                if (lr == 0) atomicAdd(&wsl[q], s);
                const u16 p1 = f2bf(e);
                const u16 p2 = f2bf(e - bf2f(p1));
                Ks[0][q][w * 16 + lr] = p1;
                Ks[1][q][w * 16 + lr] = p2;
            }
        }
        __syncthreads();

#pragma unroll
        for (int ks = 0; ks < 2; ++ks) {
            const short8b b1 = *reinterpret_cast<const short8b*>(
                &Vtl[0][w * 16 + lr][ks * 32 + lg * 8]);
            const short8b b2 = *reinterpret_cast<const short8b*>(
                &Vtl[1][w * 16 + lr][ks * 32 + lg * 8]);
#pragma unroll
            for (int qt = 0; qt < 3; ++qt) {
                const short8b a1 = *reinterpret_cast<const short8b*>(
                    &Ks[0][qt * 16 + lr][ks * 32 + lg * 8]);
                const short8b a2 = *reinterpret_cast<const short8b*>(
                    &Ks[1][qt * 16 + lr][ks * 32 + lg * 8]);
                pvacc[qt] = __builtin_amdgcn_mfma_f32_16x16x32_bf16(a1, b1, pvacc[qt], 0, 0, 0);
                pvacc[qt] = __builtin_amdgcn_mfma_f32_16x16x32_bf16(a2, b1, pvacc[qt], 0, 0, 0);
                pvacc[qt] = __builtin_amdgcn_mfma_f32_16x16x32_bf16(a1, b2, pvacc[qt], 0, 0, 0);
            }
        }
    }

#pragma unroll
    for (int qt = 0; qt < 3; ++qt) {
#pragma unroll
        for (int r = 0; r < 4; ++r) {
            const int q = qt * 16 + lg * 4 + r;
            if (q < NTOP)
                atomicAdd(&uacc[((size_t)bh * NTOP + q) * DHD + w * 16 + lr],
                          pvacc[qt][r]);
        }
    }
    if (tid < NTOP) atomicAdd(&wsum[bh * NTOP + tid], wsl[tid]);
}

// ---------------------------------------------------------------------------
// K5: finalize+base fused. Blocks <320: delta = uacc/wsum - vmean (flat).
// Blocks 320..2367: broadcast meanout to all output rows (meanout was
// computed in topk_kernel — an earlier dispatch).
// ---------------------------------------------------------------------------
__global__ __launch_bounds__(256) void finalize_base(
    const float* __restrict__ wsum, const float* __restrict__ uacc,
    const float* __restrict__ VmeanRaw, const float* __restrict__ meanout,
    float* __restrict__ delta, float* __restrict__ out)
{
    const int blk = blockIdx.x;
    if (blk < 320) {
        const int idx = blk * 256 + threadIdx.x;
        const int bh = idx / 2560;
        const int rem = idx - bh * 2560;
        const int q = rem >> 6, d = rem & 63;
        const float vm = VmeanRaw[bh * DHD + d] * (1.0f / (float)LSEQ);
        delta[idx] = uacc[idx] / wsum[bh * NTOP + q] - vm;
    } else {
        const int total4 = BATCH * LSEQ * (DMODEL / 4);   // 2^20
        for (int i = (blk - 320) * 256 + threadIdx.x; i < total4; i += 2048 * 256) {
            const int row = i >> 7;
            const int b = row >> 11;
            const int c = i & 127;
            reinterpret_cast<float4*>(out)[i] =
                reinterpret_cast<const float4*>(meanout)[b * 128 + c];
        }
    }
}

// ---------------------------------------------------------------------------
// K6: scatter-add selected rows: out[b,l,:] += delta[bh,u] @ Wo_h^T.
// ---------------------------------------------------------------------------
__global__ __launch_bounds__(128) void out_scatter(
    const int* __restrict__ topidx, const float* __restrict__ delta,
    const float* __restrict__ Wo, float* __restrict__ out)
{
    const int bh = blockIdx.x;
    const int u  = blockIdx.y;
    const int b = bh >> 3, h = bh & 7;
    const int l = topidx[bh * NTOP + u];

    __shared__ float dl[DHD];
    if (threadIdx.x < DHD)
        dl[threadIdx.x] = delta[((size_t)bh * NTOP + u) * DHD + threadIdx.x];
    __syncthreads();

    float* orow = out + ((size_t)b * LSEQ + l) * DMODEL;
#pragma unroll
    for (int c = 0; c < 4; ++c) {
        const int n = threadIdx.x * 4 + c;
        const float4* wr4 = reinterpret_cast<const float4*>(
            Wo + (size_t)n * DMODEL + h * DHD);
        float a = 0.f;
#pragma unroll
        for (int dd = 0; dd < 16; ++dd) {
            const float4 wv = wr4[dd];
            a += dl[dd * 4 + 0] * wv.x + dl[dd * 4 + 1] * wv.y +
                 dl[dd * 4 + 2] * wv.z + dl[dd * 4 + 3] * wv.w;
        }
        atomicAdd(&orow[n], a);
    }
}

// ---------------------------------------------------------------------------
extern "C" void kernel_launch(void* const* d_in, const int* in_sizes, int n_in,
                              void* d_out, int out_size, void* d_ws, size_t ws_size,
                              hipStream_t stream)
{
    (void)in_sizes; (void)n_in; (void)out_size; (void)ws_size;
    const float* x     = (const float*)d_in[0];
    const float* ctxin = (const float*)d_in[1];
    const float* Wq    = (const float*)d_in[2];
    const float* bq    = (const float*)d_in[3];
    const float* Wk    = (const float*)d_in[4];
    const float* bk    = (const float*)d_in[5];
    const float* Wv    = (const float*)d_in[6];
    const float* bv    = (const float*)d_in[7];
    const float* Wo    = (const float*)d_in[8];
    const float* bo    = (const float*)d_in[9];
    const int*   idxs  = (const int*)d_in[10];
    float* out = (float*)d_out;

    char* ws = (char*)d_ws;
    size_t off = 0;
    auto alloc = [&](size_t bytes) -> void* {
        void* p = ws + off;
        off += (bytes + 255) & ~(size_t)255;
        return p;
    };

    const size_t qkv_bytes = (size_t)BATCH * NH * LSEQ * DHD * sizeof(float);
    float*         Qt       = (float*)alloc(qkv_bytes);
    float*         Kt       = (float*)alloc(qkv_bytes);
    float*         Vt       = (float*)alloc(qkv_bytes);
    float*         Mbuf     = (float*)alloc((size_t)BATCH * NH * LSEQ * sizeof(float));
    float*         VmeanRaw = (float*)alloc((size_t)BATCH * NH * DHD * sizeof(float));
    float*         meanout  = (float*)alloc((size_t)BATCH * DMODEL * sizeof(float));
    float*         delta    = (float*)alloc((size_t)BATCH * NH * NTOP * DHD * sizeof(float));
    int*           topidx   = (int*)alloc((size_t)BATCH * NH * NTOP * sizeof(int));
    float*         wsum     = (float*)alloc((size_t)BATCH * NH * NTOP * sizeof(float));
    float*         uacc     = (float*)alloc((size_t)BATCH * NH * NTOP * DHD * sizeof(float));
    u16*           xsP      = (u16*)alloc(ASTRIDE * 3 * 2);
    u16*           csP      = (u16*)alloc(ASTRIDE * 3 * 2);
    u16*           wqP      = (u16*)alloc(WSTRIDE * 3 * 2);
    u16*           wkP      = (u16*)alloc(WSTRIDE * 3 * 2);
    u16*           wvP      = (u16*)alloc(WSTRIDE * 3 * 2);

    split3_all<<<2048, 256, 0, stream>>>(x, ctxin, Wq, Wk, Wv,
                                         xsP, csP, wqP, wkP, wvP,
                                         VmeanRaw, uacc, wsum);

    gemm_all<<<dim3(256, 3), 256, 0, stream>>>(
        xsP, csP, wqP, wkP, wvP, bq, bk, bv, Qt, Kt, Vt, VmeanRaw);

    score_kernel<<<(BATCH * NH * LSEQ) / 4, 256, 0, stream>>>(
        Qt, Kt, idxs, Mbuf);

    topk_kernel<<<36, 256, 0, stream>>>(
        Mbuf, topidx, VmeanRaw, Wo, bo, meanout);

    attn_partial<<<dim3(BATCH * NH, NSEG), 256, 0, stream>>>(
        Qt, Kt, Vt, topidx, wsum, uacc);

    finalize_base<<<2368, 256, 0, stream>>>(
        wsum, uacc, VmeanRaw, meanout, delta, out);

    out_scatter<<<dim3(BATCH * NH, NTOP), 128, 0, stream>>>(
        topidx, delta, Wo, out);
}